// Round 2
// baseline (2258.918 us; speedup 1.0000x reference)
//
#include <hip/hip_runtime.h>
#include <cstdint>
#include <cstddef>

typedef __bf16 bf16_t;
typedef __attribute__((ext_vector_type(8))) __bf16 bf16x8;
typedef __attribute__((ext_vector_type(4))) float f32x4;

#define B_ 2
#define S_ 1024
#define D_ 1024
#define H_ 16
#define T_ 2048
#define E_ 8
#define F_ 1024
#define MOE_ROWS 5120
#define MAX_TILES 40

// ---------------- async global->LDS (16B per lane) ----------------
__device__ __forceinline__ void global_to_lds16(const void* g, void* l) {
  __builtin_amdgcn_global_load_lds(
      (__attribute__((address_space(1))) unsigned int*)(uintptr_t)g,
      (__attribute__((address_space(3))) unsigned int*)(unsigned int)(uintptr_t)l,
      16, 0, 0);
}

// ---------------- fp32 -> split bf16 (hi, lo) ----------------
__device__ __forceinline__ void split2(float x, bf16_t& h, bf16_t& l) {
  h = (bf16_t)x;
  l = (bf16_t)(x - (float)h);
}

__global__ __launch_bounds__(256) void k_cvt2(const float* __restrict__ s,
    bf16_t* __restrict__ dh, bf16_t* __restrict__ dl, int n) {
  int i = (blockIdx.x * 256 + threadIdx.x) * 4;
  if (i >= n) return;
  float4 v = *(const float4*)(s + i);
  union { bf16_t h[4]; ushort4 u; } ch, cl;
  split2(v.x, ch.h[0], cl.h[0]);
  split2(v.y, ch.h[1], cl.h[1]);
  split2(v.z, ch.h[2], cl.h[2]);
  split2(v.w, ch.h[3], cl.h[3]);
  *(ushort4*)(dh + i) = ch.u;
  *(ushort4*)(dl + i) = cl.u;
}

// ---------------- LayerNorm (one block per row of 1024) ----------------
__global__ __launch_bounds__(256) void k_ln(const float* __restrict__ x,
    const float* __restrict__ g, const float* __restrict__ b,
    float* __restrict__ of, bf16_t* __restrict__ obh, bf16_t* __restrict__ obl) {
  int t = blockIdx.x, tid = threadIdx.x;
  const float4* xr = (const float4*)(x + (size_t)t * D_);
  float4 v = xr[tid];
  float s = v.x + v.y + v.z + v.w;
  float s2 = v.x * v.x + v.y * v.y + v.z * v.z + v.w * v.w;
#pragma unroll
  for (int o = 32; o; o >>= 1) { s += __shfl_xor(s, o, 64); s2 += __shfl_xor(s2, o, 64); }
  __shared__ float rs[4], rs2[4];
  if ((tid & 63) == 0) { rs[tid >> 6] = s; rs2[tid >> 6] = s2; }
  __syncthreads();
  s = rs[0] + rs[1] + rs[2] + rs[3];
  s2 = rs2[0] + rs2[1] + rs2[2] + rs2[3];
  float mu = s * (1.f / D_);
  float var = s2 * (1.f / D_) - mu * mu;
  float r = rsqrtf(var + 1e-5f);
  float4 gg = ((const float4*)g)[tid];
  float4 bb = ((const float4*)b)[tid];
  float4 o;
  o.x = (v.x - mu) * r * gg.x + bb.x;
  o.y = (v.y - mu) * r * gg.y + bb.y;
  o.z = (v.z - mu) * r * gg.z + bb.z;
  o.w = (v.w - mu) * r * gg.w + bb.w;
  if (of) ((float4*)(of + (size_t)t * D_))[tid] = o;
  if (obh) {
    union { bf16_t h[4]; ushort4 u; } ch, cl;
    split2(o.x, ch.h[0], cl.h[0]);
    split2(o.y, ch.h[1], cl.h[1]);
    split2(o.z, ch.h[2], cl.h[2]);
    split2(o.w, ch.h[3], cl.h[3]);
    *(ushort4*)(obh + (size_t)t * D_ + tid * 4) = ch.u;
    *(ushort4*)(obl + (size_t)t * D_ + tid * 4) = cl.u;
  }
}

// ---- split-precision GEMM: C[M,N] (+)= A[M,K] @ B[N,K]^T + bias ----
// A,B given as (hi,lo) bf16 planes; computes hi*hi + hi*lo + lo*hi (rel err ~1e-5)
__global__ __launch_bounds__(256) void k_gemm(const bf16_t* __restrict__ Ah,
    const bf16_t* __restrict__ Al, const bf16_t* __restrict__ Bh,
    const bf16_t* __restrict__ Bl, float* __restrict__ C,
    const float* __restrict__ bias, int M, int N, int K, int addC) {
  __shared__ __align__(16) bf16_t Ash[128 * 32];
  __shared__ __align__(16) bf16_t Asl[128 * 32];
  __shared__ __align__(16) bf16_t Bsh[128 * 32];
  __shared__ __align__(16) bf16_t Bsl[128 * 32];
  const int tid = threadIdx.x;
  const int wave = tid >> 6, lane = tid & 63;
  const int wm = (wave >> 1) << 6, wn = (wave & 1) << 6;
  const int lr = lane & 15, kg = lane >> 4;
  const int row0 = blockIdx.y * 128, col0 = blockIdx.x * 128;
  f32x4 acc[4][4] = {};
  for (int k0 = 0; k0 < K; k0 += 32) {
#pragma unroll
    for (int c = 0; c < 2; c++) {
      int o = c * 4096 + tid * 16;
      int r = o >> 6, cb = (o & 63) >> 1;
      size_t ga = (size_t)(row0 + r) * K + k0 + cb;
      size_t gb = (size_t)(col0 + r) * K + k0 + cb;
      global_to_lds16(Ah + ga, (char*)Ash + o);
      global_to_lds16(Al + ga, (char*)Asl + o);
      global_to_lds16(Bh + gb, (char*)Bsh + o);
      global_to_lds16(Bl + gb, (char*)Bsl + o);
    }
    __syncthreads();
    bf16x8 ah[4], al[4], bh[4], bl[4];
#pragma unroll
    for (int i = 0; i < 4; i++) {
      int ra = (wm + i * 16 + lr) * 32 + kg * 8;
      int rb = (wn + i * 16 + lr) * 32 + kg * 8;
      ah[i] = *(const bf16x8*)&Ash[ra];
      al[i] = *(const bf16x8*)&Asl[ra];
      bh[i] = *(const bf16x8*)&Bsh[rb];
      bl[i] = *(const bf16x8*)&Bsl[rb];
    }
#pragma unroll
    for (int mi = 0; mi < 4; mi++)
#pragma unroll
      for (int ni = 0; ni < 4; ni++) {
        acc[mi][ni] = __builtin_amdgcn_mfma_f32_16x16x32_bf16(ah[mi], bh[ni], acc[mi][ni], 0, 0, 0);
        acc[mi][ni] = __builtin_amdgcn_mfma_f32_16x16x32_bf16(ah[mi], bl[ni], acc[mi][ni], 0, 0, 0);
        acc[mi][ni] = __builtin_amdgcn_mfma_f32_16x16x32_bf16(al[mi], bh[ni], acc[mi][ni], 0, 0, 0);
      }
    __syncthreads();
  }
#pragma unroll
  for (int mi = 0; mi < 4; mi++) {
#pragma unroll
    for (int r = 0; r < 4; r++) {
      int m = row0 + wm + mi * 16 + kg * 4 + r;
      if (m >= M) continue;
      float* crow = C + (size_t)m * N;
#pragma unroll
      for (int ni = 0; ni < 4; ni++) {
        int n = col0 + wn + ni * 16 + lr;
        float v = acc[mi][ni][r];
        if (bias) v += bias[n];
        if (addC) crow[n] += v; else crow[n] = v;
      }
    }
  }
}

// ---------------- grouped split-precision GEMM over expert tiles ----------------
__global__ __launch_bounds__(256) void k_gemm_grp(const bf16_t* __restrict__ Ah,
    const bf16_t* __restrict__ Al, const bf16_t* __restrict__ Bbh,
    const bf16_t* __restrict__ Bbl, float* __restrict__ C,
    const float* __restrict__ biasbase,
    const int* __restrict__ tile_e, const int* __restrict__ tile_r0,
    const int* __restrict__ tile_rend, const int* __restrict__ ntl,
    int N, int K) {
  __shared__ __align__(16) bf16_t Ash[128 * 32];
  __shared__ __align__(16) bf16_t Asl[128 * 32];
  __shared__ __align__(16) bf16_t Bsh[128 * 32];
  __shared__ __align__(16) bf16_t Bsl[128 * 32];
  int ti = blockIdx.y;
  if (ti >= *ntl) return;
  const int e = tile_e[ti];
  const int row0 = tile_r0[ti];
  const int rend = tile_rend[ti];
  const bf16_t* Bh = Bbh + (size_t)e * N * K;
  const bf16_t* Bl = Bbl + (size_t)e * N * K;
  const float* bias = biasbase + (size_t)e * N;
  const int tid = threadIdx.x;
  const int wave = tid >> 6, lane = tid & 63;
  const int wm = (wave >> 1) << 6, wn = (wave & 1) << 6;
  const int lr = lane & 15, kg = lane >> 4;
  const int col0 = blockIdx.x * 128;
  f32x4 acc[4][4] = {};
  for (int k0 = 0; k0 < K; k0 += 32) {
#pragma unroll
    for (int c = 0; c < 2; c++) {
      int o = c * 4096 + tid * 16;
      int r = o >> 6, cb = (o & 63) >> 1;
      size_t ga = (size_t)(row0 + r) * K + k0 + cb;
      size_t gb = (size_t)(col0 + r) * K + k0 + cb;
      global_to_lds16(Ah + ga, (char*)Ash + o);
      global_to_lds16(Al + ga, (char*)Asl + o);
      global_to_lds16(Bh + gb, (char*)Bsh + o);
      global_to_lds16(Bl + gb, (char*)Bsl + o);
    }
    __syncthreads();
    bf16x8 ah[4], al[4], bh[4], bl[4];
#pragma unroll
    for (int i = 0; i < 4; i++) {
      int ra = (wm + i * 16 + lr) * 32 + kg * 8;
      int rb = (wn + i * 16 + lr) * 32 + kg * 8;
      ah[i] = *(const bf16x8*)&Ash[ra];
      al[i] = *(const bf16x8*)&Asl[ra];
      bh[i] = *(const bf16x8*)&Bsh[rb];
      bl[i] = *(const bf16x8*)&Bsl[rb];
    }
#pragma unroll
    for (int mi = 0; mi < 4; mi++)
#pragma unroll
      for (int ni = 0; ni < 4; ni++) {
        acc[mi][ni] = __builtin_amdgcn_mfma_f32_16x16x32_bf16(ah[mi], bh[ni], acc[mi][ni], 0, 0, 0);
        acc[mi][ni] = __builtin_amdgcn_mfma_f32_16x16x32_bf16(ah[mi], bl[ni], acc[mi][ni], 0, 0, 0);
        acc[mi][ni] = __builtin_amdgcn_mfma_f32_16x16x32_bf16(al[mi], bh[ni], acc[mi][ni], 0, 0, 0);
      }
    __syncthreads();
  }
#pragma unroll
  for (int mi = 0; mi < 4; mi++) {
#pragma unroll
    for (int r = 0; r < 4; r++) {
      int m = row0 + wm + mi * 16 + kg * 4 + r;
      if (m >= rend) continue;
      float* crow = C + (size_t)m * N;
#pragma unroll
      for (int ni = 0; ni < 4; ni++) {
        int n = col0 + wn + ni * 16 + lr;
        crow[n] = acc[mi][ni][r] + bias[n];
      }
    }
  }
}

// ---------------- attention: split-K partial (chunks of 4 key-tiles) ----------------
__global__ __launch_bounds__(64) void k_attn_part(const float* __restrict__ qkv,
    float* __restrict__ po, float* __restrict__ pm, float* __restrict__ pl) {
  int blk = blockIdx.x;                   // ((b*H + h)*16 + qt)*4 + ck
  int ck = blk & 3;
  int qt = (blk >> 2) & 15;
  int h = (blk >> 6) & 15;
  int b = blk >> 10;
  if (ck * 4 > qt) return;
  int lane = threadIdx.x;
  int qi = qt * 64 + lane;
  size_t tq = (size_t)(b * S_ + qi);
  const float* qrow = qkv + tq * 3072 + h * 64;
  float q[64];
#pragma unroll
  for (int d = 0; d < 64; d++) q[d] = qrow[d] * 0.125f;   // fold 1/sqrt(64)
  float o[64];
#pragma unroll
  for (int d = 0; d < 64; d++) o[d] = 0.f;
  float m = -1e30f, l = 0.f;
  __shared__ float Ks[64][64];
  __shared__ float Vs[64][64];
  int kt_end = (ck * 4 + 4 < qt + 1) ? ck * 4 + 4 : qt + 1;
  for (int kt = ck * 4; kt < kt_end; kt++) {
    __syncthreads();
#pragma unroll 4
    for (int rr = 0; rr < 64; rr++) {
      size_t kk = (size_t)(b * S_ + kt * 64 + rr) * 3072 + 1024 + h * 64 + lane;
      Ks[rr][lane] = qkv[kk];
      Vs[rr][lane] = qkv[kk + 1024];
    }
    __syncthreads();
    int kbase = kt * 64;
    for (int jc = 0; jc < 4; jc++) {
      float s[16]; float cmax = -1e30f;
#pragma unroll
      for (int jj = 0; jj < 16; jj++) {
        int j = jc * 16 + jj;
        float a = 0.f;
#pragma unroll
        for (int d = 0; d < 64; d++) a += q[d] * Ks[j][d];
        s[jj] = (kbase + j <= qi) ? a : -1e30f;
        cmax = fmaxf(cmax, s[jj]);
      }
      if (cmax > -1e29f) {
        float mn = fmaxf(m, cmax);
        float al = __expf(m - mn);
        l *= al;
#pragma unroll
        for (int d = 0; d < 64; d++) o[d] *= al;
        m = mn;
#pragma unroll
        for (int jj = 0; jj < 16; jj++) {
          float pv = __expf(s[jj] - mn);
          l += pv;
          int j = jc * 16 + jj;
#pragma unroll
          for (int d = 0; d < 64; d++) o[d] += pv * Vs[j][d];
        }
      }
    }
  }
  size_t slot = (size_t)blk;
  pm[slot * 64 + lane] = m;
  pl[slot * 64 + lane] = l;
  float* orow = po + (slot * 64 + lane) * 64;
#pragma unroll
  for (int d = 0; d < 64; d++) orow[d] = o[d];
}

// ---------------- attention: merge partials -> ctx (split bf16) ----------------
__global__ __launch_bounds__(64) void k_attn_merge(const float* __restrict__ po,
    const float* __restrict__ pm, const float* __restrict__ pl,
    bf16_t* __restrict__ ctxh, bf16_t* __restrict__ ctxl) {
  int blk = blockIdx.x;                 // (b*H + h)*16 + qt
  int qt = blk & 15;
  int h = (blk >> 4) & 15;
  int b = blk >> 8;
  int lane = threadIdx.x;
  int nck = qt / 4 + 1;
  size_t sbase = (size_t)blk * 4;
  float m = -1e30f;
  for (int ck = 0; ck < nck; ck++) m = fmaxf(m, pm[(sbase + ck) * 64 + lane]);
  float l = 0.f;
  float o[64];
#pragma unroll
  for (int d = 0; d < 64; d++) o[d] = 0.f;
  for (int ck = 0; ck < nck; ck++) {
    size_t sl = sbase + ck;
    float a = __expf(pm[sl * 64 + lane] - m);
    l += a * pl[sl * 64 + lane];
    const float* orow = po + (sl * 64 + lane) * 64;
#pragma unroll
    for (int d = 0; d < 64; d++) o[d] += a * orow[d];
  }
  float inv = 1.f / l;
  int t = b * S_ + qt * 64 + lane;
  bf16_t* ch = ctxh + (size_t)t * D_ + h * 64;
  bf16_t* cl = ctxl + (size_t)t * D_ + h * 64;
#pragma unroll
  for (int d = 0; d < 64; d++) {
    bf16_t hh, ll;
    split2(o[d] * inv, hh, ll);
    ch[d] = hh; cl[d] = ll;
  }
}

// ---------------- gate + grouped top-k routing (one wave per token, fp32 exact) ----------------
__global__ __launch_bounds__(64) void k_route(const float* __restrict__ h2,
    const float* __restrict__ gw, int* __restrict__ eidx, float* __restrict__ ew,
    int* __restrict__ cnt) {
  int t = blockIdx.x, lane = threadIdx.x;
  const float* x = h2 + (size_t)t * D_;
  float lg[8];
#pragma unroll
  for (int e = 0; e < 8; e++) {
    const float* w = gw + e * D_;
    float a = 0.f;
    for (int d = lane; d < D_; d += 64) a += x[d] * w[d];
#pragma unroll
    for (int o = 32; o; o >>= 1) a += __shfl_xor(a, o, 64);
    lg[e] = a;
  }
  if (lane == 0) {
    float mx = lg[0];
    for (int e = 1; e < 8; e++) mx = fmaxf(mx, lg[e]);
    float p[8], sum = 0.f;
    for (int e = 0; e < 8; e++) { p[e] = __expf(lg[e] - mx); sum += p[e]; }
    float inv = 1.f / sum;
    for (int e = 0; e < 8; e++) p[e] *= inv;
    float gs[4];
    for (int gi = 0; gi < 4; gi++) gs[gi] = fmaxf(p[2 * gi], p[2 * gi + 1]);
    int g0 = 0;
    for (int gi = 1; gi < 4; gi++) if (gs[gi] > gs[g0]) g0 = gi;
    int g1 = -1;
    for (int gi = 0; gi < 4; gi++) {
      if (gi == g0) continue;
      if (g1 < 0 || gs[gi] > gs[g1]) g1 = gi;
    }
    int i0 = -1, i1 = -1; float v0 = -1.f, v1 = -1.f;
    for (int e = 0; e < 8; e++) {
      int gi = e >> 1;
      if (gi != g0 && gi != g1) continue;
      if (p[e] > v0) { v1 = v0; i1 = i0; v0 = p[e]; i0 = e; }
      else if (p[e] > v1) { v1 = p[e]; i1 = e; }
    }
    eidx[2 * t] = i0; eidx[2 * t + 1] = i1;
    ew[2 * t] = v0; ew[2 * t + 1] = v1;
    atomicAdd(&cnt[i0], 1);
    atomicAdd(&cnt[i1], 1);
  }
}

// ---------------- expert offsets + tile table (128-aligned segments) ----------------
__global__ void k_offsets(const int* __restrict__ cnt, int* __restrict__ poff,
                          int* __restrict__ te, int* __restrict__ tr0,
                          int* __restrict__ trend, int* __restrict__ ntl) {
  if (threadIdx.x != 0 || blockIdx.x != 0) return;
  int offv = 0, nt = 0;
  for (int e = 0; e < 8; e++) {
    poff[e] = offv;
    int c = cnt[e];
    int ntile = (c + 127) >> 7;
    for (int i = 0; i < ntile; i++) {
      te[nt] = e; tr0[nt] = offv + i * 128; trend[nt] = offv + c; nt++;
    }
    offv += ntile << 7;
  }
  poff[8] = offv;
  *ntl = nt;
}

__global__ __launch_bounds__(256) void k_fill(const int* __restrict__ eidx,
    const int* __restrict__ poff,
    int* __restrict__ cur, int* __restrict__ rowtok, int* __restrict__ postk) {
  int t = blockIdx.x * 256 + threadIdx.x;
  if (t >= T_) return;
#pragma unroll
  for (int k = 0; k < 2; k++) {
    int e = eidx[2 * t + k];
    int r = atomicAdd(&cur[e], 1);
    int pos = poff[e] + r;
    rowtok[pos] = t;
    postk[2 * t + k] = pos;
  }
}

__global__ __launch_bounds__(256) void k_gather(const int* __restrict__ rowtok,
    const bf16_t* __restrict__ h2h, const bf16_t* __restrict__ h2l,
    bf16_t* __restrict__ amh, bf16_t* __restrict__ aml) {
  int rrow = blockIdx.x;
  int tid = threadIdx.x;
  int t = rowtok[rrow];
  ushort4* dh = (ushort4*)(amh + (size_t)rrow * D_);
  ushort4* dl = (ushort4*)(aml + (size_t)rrow * D_);
  if (t < 0) {
    dh[tid] = make_ushort4(0, 0, 0, 0);
    dl[tid] = make_ushort4(0, 0, 0, 0);
  } else {
    dh[tid] = ((const ushort4*)(h2h + (size_t)t * D_))[tid];
    dl[tid] = ((const ushort4*)(h2l + (size_t)t * D_))[tid];
  }
}

__global__ __launch_bounds__(256) void k_swiglu(const float* __restrict__ h1,
    const float* __restrict__ h3, bf16_t* __restrict__ acth,
    bf16_t* __restrict__ actl, int n4) {
  int i = blockIdx.x * 256 + threadIdx.x;
  if (i >= n4) return;
  float4 a = ((const float4*)h1)[i];
  float4 c = ((const float4*)h3)[i];
  float4 o;
  o.x = a.x / (1.f + __expf(-a.x)) * c.x;
  o.y = a.y / (1.f + __expf(-a.y)) * c.y;
  o.z = a.z / (1.f + __expf(-a.z)) * c.z;
  o.w = a.w / (1.f + __expf(-a.w)) * c.w;
  union { bf16_t h[4]; ushort4 u; } ch, cl;
  split2(o.x, ch.h[0], cl.h[0]);
  split2(o.y, ch.h[1], cl.h[1]);
  split2(o.z, ch.h[2], cl.h[2]);
  split2(o.w, ch.h[3], cl.h[3]);
  ((ushort4*)acth)[i] = ch.u;
  ((ushort4*)actl)[i] = cl.u;
}

__global__ __launch_bounds__(256) void k_scatter(const float* __restrict__ outm,
    const int* __restrict__ postk, const float* __restrict__ ewt,
    float* __restrict__ y) {
  int t = blockIdx.x, tid = threadIdx.x;
  int p0 = postk[2 * t], p1 = postk[2 * t + 1];
  float w0 = ewt[2 * t], w1 = ewt[2 * t + 1];
  float4* yr = (float4*)(y + (size_t)t * D_);
  const float4* a = (const float4*)(outm + (size_t)p0 * D_);
  const float4* b = (const float4*)(outm + (size_t)p1 * D_);
  float4 v = yr[tid], va = a[tid], vb = b[tid];
  v.x += w0 * va.x + w1 * vb.x;
  v.y += w0 * va.y + w1 * vb.y;
  v.z += w0 * va.z + w1 * vb.z;
  v.w += w0 * va.w + w1 * vb.w;
  yr[tid] = v;
}

extern "C" void kernel_launch(void* const* d_in, const int* in_sizes, int n_in,
                              void* d_out, int out_size, void* d_ws, size_t ws_size,
                              hipStream_t stream) {
  const float* src  = (const float*)d_in[0];
  const float* qkvw = (const float*)d_in[1];
  const float* qkvb = (const float*)d_in[2];
  const float* outw = (const float*)d_in[3];
  const float* outb = (const float*)d_in[4];
  const float* n1g  = (const float*)d_in[5];
  const float* n1b  = (const float*)d_in[6];
  const float* n2g  = (const float*)d_in[7];
  const float* n2b  = (const float*)d_in[8];
  const float* gw   = (const float*)d_in[9];
  const float* ew1  = (const float*)d_in[10];
  const float* eb1  = (const float*)d_in[11];
  const float* ew2  = (const float*)d_in[12];
  const float* eb2  = (const float*)d_in[13];
  const float* ew3  = (const float*)d_in[14];
  const float* eb3  = (const float*)d_in[15];
  const float* sw1  = (const float*)d_in[16];
  const float* sb1  = (const float*)d_in[17];
  const float* sw2  = (const float*)d_in[18];
  const float* sb2  = (const float*)d_in[19];
  const float* sw3  = (const float*)d_in[20];
  const float* sb3  = (const float*)d_in[21];
  const float* fng  = (const float*)d_in[22];
  const float* fnb  = (const float*)d_in[23];
  float* outp = (float*)d_out;

  char* base = (char*)d_ws;
  size_t off = 0;
  auto alloc = [&](size_t bytes) -> void* {
    off = (off + 255) & ~(size_t)255;
    void* r = base + off;
    off += bytes;
    return r;
  };
  // weight hi/lo planes (per-layer converted)
  bf16_t* wqkv_h = (bf16_t*)alloc((size_t)3072 * 1024 * 2);
  bf16_t* wqkv_l = (bf16_t*)alloc((size_t)3072 * 1024 * 2);
  bf16_t* wout_h = (bf16_t*)alloc((size_t)1024 * 1024 * 2);
  bf16_t* wout_l = (bf16_t*)alloc((size_t)1024 * 1024 * 2);
  bf16_t* we1_h  = (bf16_t*)alloc((size_t)8 * 1024 * 1024 * 2);
  bf16_t* we1_l  = (bf16_t*)alloc((size_t)8 * 1024 * 1024 * 2);
  bf16_t* we2_h  = (bf16_t*)alloc((size_t)8 * 1024 * 1024 * 2);
  bf16_t* we2_l  = (bf16_t*)alloc((size_t)8 * 1024 * 1024 * 2);
  bf16_t* we3_h  = (bf16_t*)alloc((size_t)8 * 1024 * 1024 * 2);
  bf16_t* we3_l  = (bf16_t*)alloc((size_t)8 * 1024 * 1024 * 2);
  bf16_t* wsh1_h = (bf16_t*)alloc((size_t)1024 * 1024 * 2);
  bf16_t* wsh1_l = (bf16_t*)alloc((size_t)1024 * 1024 * 2);
  bf16_t* wsh2_h = (bf16_t*)alloc((size_t)1024 * 1024 * 2);
  bf16_t* wsh2_l = (bf16_t*)alloc((size_t)1024 * 1024 * 2);
  bf16_t* wsh3_h = (bf16_t*)alloc((size_t)1024 * 1024 * 2);
  bf16_t* wsh3_l = (bf16_t*)alloc((size_t)1024 * 1024 * 2);
  float*  y    = (float*)alloc((size_t)T_ * D_ * 4);
  float*  lnf  = (float*)alloc((size_t)T_ * D_ * 4);
  bf16_t* lnb_h = (bf16_t*)alloc((size_t)T_ * D_ * 2);
  bf16_t* lnb_l = (bf16_t*)alloc((size_t)T_ * D_ * 2);
  bf16_t* ctx_h = (bf16_t*)alloc((size_t)T_ * D_ * 2);
  bf16_t* ctx_l = (bf16_t*)alloc((size_t)T_ * D_ * 2);
  char* regA   = (char*)alloc((size_t)2 * MOE_ROWS * 1024 * 4);  // 42MB union region
  float* qkvbuf = (float*)regA;                                   // 2048x3072 f32
  float* h1     = (float*)regA;                                   // 5120x1024 f32
  float* h3     = (float*)(regA + (size_t)MOE_ROWS * 1024 * 4);
  float* outm   = (float*)regA;                                   // after h1 dead
  // union region: attention split-K scratch  vs  MoE act/gather planes
  char* regU = (char*)alloc((size_t)4 * MOE_ROWS * 1024 * 2);     // 40MB
  float* po = (float*)regU;                                       // 2048*64*64 f32 = 33.5MB
  bf16_t* act_h  = (bf16_t*)regU;
  bf16_t* act_l  = (bf16_t*)(regU + (size_t)MOE_ROWS * 1024 * 2);
  bf16_t* amoe_h = (bf16_t*)(regU + (size_t)2 * MOE_ROWS * 1024 * 2);
  bf16_t* amoe_l = (bf16_t*)(regU + (size_t)3 * MOE_ROWS * 1024 * 2);
  float* pm = (float*)alloc((size_t)2048 * 64 * 4);
  float* pl = (float*)alloc((size_t)2048 * 64 * 4);
  int*   eidx = (int*)alloc((size_t)T_ * 2 * 4);
  float* ewt  = (float*)alloc((size_t)T_ * 2 * 4);
  int* cnt  = (int*)alloc(64);
  int* cur  = (int*)alloc(64);
  int* poff = (int*)alloc(64);
  int* te   = (int*)alloc(256);
  int* tr0  = (int*)alloc(256);
  int* trend = (int*)alloc(256);
  int* ntl  = (int*)alloc(16);
  int* rowtok = (int*)alloc((size_t)MOE_ROWS * 4);
  int* postk  = (int*)alloc((size_t)T_ * 2 * 4);
  (void)ws_size; (void)in_sizes; (void)n_in; (void)out_size;

  // y = src
  (void)hipMemcpyAsync(y, src, (size_t)T_ * D_ * 4, hipMemcpyDeviceToDevice, stream);

  for (int l = 0; l < 2; l++) {
    size_t lf = (size_t)l;
    // weight conversion for this layer (fp32 -> hi/lo bf16 planes)
    k_cvt2<<<3072, 256, 0, stream>>>(qkvw + lf * 3072 * 1024, wqkv_h, wqkv_l, 3072 * 1024);
    k_cvt2<<<1024, 256, 0, stream>>>(outw + lf * 1024 * 1024, wout_h, wout_l, 1024 * 1024);
    k_cvt2<<<8192, 256, 0, stream>>>(ew1 + lf * 8 * 1024 * 1024, we1_h, we1_l, 8 * 1024 * 1024);
    k_cvt2<<<8192, 256, 0, stream>>>(ew2 + lf * 8 * 1024 * 1024, we2_h, we2_l, 8 * 1024 * 1024);
    k_cvt2<<<8192, 256, 0, stream>>>(ew3 + lf * 8 * 1024 * 1024, we3_h, we3_l, 8 * 1024 * 1024);
    k_cvt2<<<1024, 256, 0, stream>>>(sw1 + lf * 1024 * 1024, wsh1_h, wsh1_l, 1024 * 1024);
    k_cvt2<<<1024, 256, 0, stream>>>(sw2 + lf * 1024 * 1024, wsh2_h, wsh2_l, 1024 * 1024);
    k_cvt2<<<1024, 256, 0, stream>>>(sw3 + lf * 1024 * 1024, wsh3_h, wsh3_l, 1024 * 1024);

    // LN1 -> split bf16
    k_ln<<<T_, 256, 0, stream>>>(y, n1g + lf * 1024, n1b + lf * 1024,
                                 (float*)nullptr, lnb_h, lnb_l);
    // QKV projection (fp32-faithful)
    k_gemm<<<dim3(24, 16), 256, 0, stream>>>(lnb_h, lnb_l, wqkv_h, wqkv_l, qkvbuf,
                                             qkvb + lf * 3072, T_, 3072, 1024, 0);
    // attention (fp32)
    k_attn_part<<<2048, 64, 0, stream>>>(qkvbuf, po, pm, pl);
    k_attn_merge<<<512, 64, 0, stream>>>(po, pm, pl, ctx_h, ctx_l);
    // out projection, residual-add into y
    k_gemm<<<dim3(8, 16), 256, 0, stream>>>(ctx_h, ctx_l, wout_h, wout_l, y,
                                            outb + lf * 1024, T_, 1024, 1024, 1);
    // LN2 -> f32 + split bf16
    k_ln<<<T_, 256, 0, stream>>>(y, n2g + lf * 1024, n2b + lf * 1024, lnf, lnb_h, lnb_l);

    // routing (fp32 exact)
    (void)hipMemsetAsync(cnt, 0, 64, stream);
    (void)hipMemsetAsync(cur, 0, 64, stream);
    (void)hipMemsetAsync(rowtok, 0xFF, (size_t)MOE_ROWS * 4, stream);
    k_route<<<T_, 64, 0, stream>>>(lnf, gw + lf * 8 * 1024, eidx, ewt, cnt);
    k_offsets<<<1, 1, 0, stream>>>(cnt, poff, te, tr0, trend, ntl);
    k_fill<<<8, 256, 0, stream>>>(eidx, poff, cur, rowtok, postk);
    k_gather<<<MOE_ROWS, 256, 0, stream>>>(rowtok, lnb_h, lnb_l, amoe_h, amoe_l);

    // routed experts
    k_gemm_grp<<<dim3(8, MAX_TILES), 256, 0, stream>>>(amoe_h, amoe_l, we1_h, we1_l, h1,
        eb1 + lf * 8192, te, tr0, trend, ntl, 1024, 1024);
    k_gemm_grp<<<dim3(8, MAX_TILES), 256, 0, stream>>>(amoe_h, amoe_l, we3_h, we3_l, h3,
        eb3 + lf * 8192, te, tr0, trend, ntl, 1024, 1024);
    k_swiglu<<<(MOE_ROWS * 1024 / 4 + 255) / 256, 256, 0, stream>>>(h1, h3, act_h, act_l,
                                                                    MOE_ROWS * 1024 / 4);
    k_gemm_grp<<<dim3(8, MAX_TILES), 256, 0, stream>>>(act_h, act_l, we2_h, we2_l, outm,
        eb2 + lf * 8192, te, tr0, trend, ntl, 1024, 1024);
    k_scatter<<<T_, 256, 0, stream>>>(outm, postk, ewt, y);

    // shared expert (reuses h1/h3/act planes; regA free after scatter)
    k_gemm<<<dim3(8, 16), 256, 0, stream>>>(lnb_h, lnb_l, wsh1_h, wsh1_l, h1,
                                            sb1 + lf * 1024, T_, 1024, 1024, 0);
    k_gemm<<<dim3(8, 16), 256, 0, stream>>>(lnb_h, lnb_l, wsh3_h, wsh3_l, h3,
                                            sb3 + lf * 1024, T_, 1024, 1024, 0);
    k_swiglu<<<(T_ * 1024 / 4 + 255) / 256, 256, 0, stream>>>(h1, h3, act_h, act_l,
                                                              T_ * 1024 / 4);
    k_gemm<<<dim3(8, 16), 256, 0, stream>>>(act_h, act_l, wsh2_h, wsh2_l, y,
                                            sb2 + lf * 1024, T_, 1024, 1024, 1);
  }

  // final LN -> d_out (fp32)
  k_ln<<<T_, 256, 0, stream>>>(y, fng, fnb, outp, (bf16_t*)nullptr, (bf16_t*)nullptr);
}

// Round 3
// 1612.043 us; speedup vs baseline: 1.4013x; 1.4013x over previous
//
#include <hip/hip_runtime.h>
#include <cstdint>
#include <cstddef>

typedef __bf16 bf16_t;
typedef __attribute__((ext_vector_type(8))) __bf16 bf16x8;
typedef __attribute__((ext_vector_type(4))) float f32x4;

#define B_ 2
#define S_ 1024
#define D_ 1024
#define H_ 16
#define T_ 2048
#define E_ 8
#define F_ 1024
#define MOE_ROWS 5120
#define MAX_TILES 40

// ---------------- async global->LDS (16B per lane) ----------------
__device__ __forceinline__ void global_to_lds16(const void* g, void* l) {
  __builtin_amdgcn_global_load_lds(
      (__attribute__((address_space(1))) unsigned int*)(uintptr_t)g,
      (__attribute__((address_space(3))) unsigned int*)(unsigned int)(uintptr_t)l,
      16, 0, 0);
}

// ---------------- fp32 -> split bf16 (hi, lo) ----------------
__device__ __forceinline__ void split2(float x, bf16_t& h, bf16_t& l) {
  h = (bf16_t)x;
  l = (bf16_t)(x - (float)h);
}

__global__ __launch_bounds__(256) void k_cvt2(const float* __restrict__ s,
    bf16_t* __restrict__ dh, bf16_t* __restrict__ dl, int n) {
  int i = (blockIdx.x * 256 + threadIdx.x) * 4;
  if (i >= n) return;
  float4 v = *(const float4*)(s + i);
  union { bf16_t h[4]; ushort4 u; } ch, cl;
  split2(v.x, ch.h[0], cl.h[0]);
  split2(v.y, ch.h[1], cl.h[1]);
  split2(v.z, ch.h[2], cl.h[2]);
  split2(v.w, ch.h[3], cl.h[3]);
  *(ushort4*)(dh + i) = ch.u;
  *(ushort4*)(dl + i) = cl.u;
}

// strided variant: src is [8][1M] per-expert; dst row e goes to e*dststride + dstoff
__global__ __launch_bounds__(256) void k_cvt2s(const float* __restrict__ s,
    bf16_t* __restrict__ dh, bf16_t* __restrict__ dl, int n, int dstoff) {
  int i = (blockIdx.x * 256 + threadIdx.x) * 4;
  if (i >= n) return;
  int e = i >> 20;
  int r = i & 1048575;
  size_t di = (size_t)e * 2097152 + dstoff + r;
  float4 v = *(const float4*)(s + i);
  union { bf16_t h[4]; ushort4 u; } ch, cl;
  split2(v.x, ch.h[0], cl.h[0]);
  split2(v.y, ch.h[1], cl.h[1]);
  split2(v.z, ch.h[2], cl.h[2]);
  split2(v.w, ch.h[3], cl.h[3]);
  *(ushort4*)(dh + di) = ch.u;
  *(ushort4*)(dl + di) = cl.u;
}

__global__ __launch_bounds__(256) void k_catbias_e(const float* __restrict__ b1,
    const float* __restrict__ b3, float* __restrict__ d) {
  int i = blockIdx.x * 256 + threadIdx.x;   // 8*2048
  int e = i >> 11, j = i & 2047;
  d[i] = (j < 1024) ? b1[e * 1024 + j] : b3[e * 1024 + j - 1024];
}

__global__ __launch_bounds__(256) void k_catbias_s(const float* __restrict__ b1,
    const float* __restrict__ b3, float* __restrict__ d) {
  int i = blockIdx.x * 256 + threadIdx.x;   // 2048
  d[i] = (i < 1024) ? b1[i] : b3[i - 1024];
}

// ---------------- LayerNorm (one block per row of 1024) ----------------
__global__ __launch_bounds__(256) void k_ln(const float* __restrict__ x,
    const float* __restrict__ g, const float* __restrict__ b,
    float* __restrict__ of, bf16_t* __restrict__ obh, bf16_t* __restrict__ obl) {
  int t = blockIdx.x, tid = threadIdx.x;
  const float4* xr = (const float4*)(x + (size_t)t * D_);
  float4 v = xr[tid];
  float s = v.x + v.y + v.z + v.w;
  float s2 = v.x * v.x + v.y * v.y + v.z * v.z + v.w * v.w;
#pragma unroll
  for (int o = 32; o; o >>= 1) { s += __shfl_xor(s, o, 64); s2 += __shfl_xor(s2, o, 64); }
  __shared__ float rs[4], rs2[4];
  if ((tid & 63) == 0) { rs[tid >> 6] = s; rs2[tid >> 6] = s2; }
  __syncthreads();
  s = rs[0] + rs[1] + rs[2] + rs[3];
  s2 = rs2[0] + rs2[1] + rs2[2] + rs2[3];
  float mu = s * (1.f / D_);
  float var = s2 * (1.f / D_) - mu * mu;
  float r = rsqrtf(var + 1e-5f);
  float4 gg = ((const float4*)g)[tid];
  float4 bb = ((const float4*)b)[tid];
  float4 o;
  o.x = (v.x - mu) * r * gg.x + bb.x;
  o.y = (v.y - mu) * r * gg.y + bb.y;
  o.z = (v.z - mu) * r * gg.z + bb.z;
  o.w = (v.w - mu) * r * gg.w + bb.w;
  if (of) ((float4*)(of + (size_t)t * D_))[tid] = o;
  if (obh) {
    union { bf16_t h[4]; ushort4 u; } ch, cl;
    split2(o.x, ch.h[0], cl.h[0]);
    split2(o.y, ch.h[1], cl.h[1]);
    split2(o.z, ch.h[2], cl.h[2]);
    split2(o.w, ch.h[3], cl.h[3]);
    *(ushort4*)(obh + (size_t)t * D_ + tid * 4) = ch.u;
    *(ushort4*)(obl + (size_t)t * D_ + tid * 4) = cl.u;
  }
}

// ---- split-precision GEMM: C[M,N] (+)= A[M,K] @ B[N,K]^T + bias ----
__global__ __launch_bounds__(256) void k_gemm(const bf16_t* __restrict__ Ah,
    const bf16_t* __restrict__ Al, const bf16_t* __restrict__ Bh,
    const bf16_t* __restrict__ Bl, float* __restrict__ C,
    const float* __restrict__ bias, int M, int N, int K, int addC) {
  __shared__ __align__(16) bf16_t Ash[128 * 32];
  __shared__ __align__(16) bf16_t Asl[128 * 32];
  __shared__ __align__(16) bf16_t Bsh[128 * 32];
  __shared__ __align__(16) bf16_t Bsl[128 * 32];
  const int tid = threadIdx.x;
  const int wave = tid >> 6, lane = tid & 63;
  const int wm = (wave >> 1) << 6, wn = (wave & 1) << 6;
  const int lr = lane & 15, kg = lane >> 4;
  const int row0 = blockIdx.y * 128, col0 = blockIdx.x * 128;
  f32x4 acc[4][4] = {};
  for (int k0 = 0; k0 < K; k0 += 32) {
#pragma unroll
    for (int c = 0; c < 2; c++) {
      int o = c * 4096 + tid * 16;
      int r = o >> 6, cb = (o & 63) >> 1;
      size_t ga = (size_t)(row0 + r) * K + k0 + cb;
      size_t gb = (size_t)(col0 + r) * K + k0 + cb;
      global_to_lds16(Ah + ga, (char*)Ash + o);
      global_to_lds16(Al + ga, (char*)Asl + o);
      global_to_lds16(Bh + gb, (char*)Bsh + o);
      global_to_lds16(Bl + gb, (char*)Bsl + o);
    }
    __syncthreads();
    bf16x8 ah[4], al[4], bh[4], bl[4];
#pragma unroll
    for (int i = 0; i < 4; i++) {
      int ra = (wm + i * 16 + lr) * 32 + kg * 8;
      int rb = (wn + i * 16 + lr) * 32 + kg * 8;
      ah[i] = *(const bf16x8*)&Ash[ra];
      al[i] = *(const bf16x8*)&Asl[ra];
      bh[i] = *(const bf16x8*)&Bsh[rb];
      bl[i] = *(const bf16x8*)&Bsl[rb];
    }
#pragma unroll
    for (int mi = 0; mi < 4; mi++)
#pragma unroll
      for (int ni = 0; ni < 4; ni++) {
        acc[mi][ni] = __builtin_amdgcn_mfma_f32_16x16x32_bf16(ah[mi], bh[ni], acc[mi][ni], 0, 0, 0);
        acc[mi][ni] = __builtin_amdgcn_mfma_f32_16x16x32_bf16(ah[mi], bl[ni], acc[mi][ni], 0, 0, 0);
        acc[mi][ni] = __builtin_amdgcn_mfma_f32_16x16x32_bf16(al[mi], bh[ni], acc[mi][ni], 0, 0, 0);
      }
    __syncthreads();
  }
#pragma unroll
  for (int mi = 0; mi < 4; mi++) {
#pragma unroll
    for (int r = 0; r < 4; r++) {
      int m = row0 + wm + mi * 16 + kg * 4 + r;
      if (m >= M) continue;
      float* crow = C + (size_t)m * N;
#pragma unroll
      for (int ni = 0; ni < 4; ni++) {
        int n = col0 + wn + ni * 16 + lr;
        float v = acc[mi][ni][r];
        if (bias) v += bias[n];
        if (addC) crow[n] += v; else crow[n] = v;
      }
    }
  }
}

// ---------------- grouped split-precision GEMM over expert tiles ----------------
__global__ __launch_bounds__(256) void k_gemm_grp(const bf16_t* __restrict__ Ah,
    const bf16_t* __restrict__ Al, const bf16_t* __restrict__ Bbh,
    const bf16_t* __restrict__ Bbl, float* __restrict__ C,
    const float* __restrict__ biasbase,
    const int* __restrict__ tile_e, const int* __restrict__ tile_r0,
    const int* __restrict__ tile_rend, const int* __restrict__ ntl,
    int N, int K) {
  __shared__ __align__(16) bf16_t Ash[128 * 32];
  __shared__ __align__(16) bf16_t Asl[128 * 32];
  __shared__ __align__(16) bf16_t Bsh[128 * 32];
  __shared__ __align__(16) bf16_t Bsl[128 * 32];
  int ti = blockIdx.y;
  if (ti >= *ntl) return;
  const int e = tile_e[ti];
  const int row0 = tile_r0[ti];
  const int rend = tile_rend[ti];
  const bf16_t* Bh = Bbh + (size_t)e * N * K;
  const bf16_t* Bl = Bbl + (size_t)e * N * K;
  const float* bias = biasbase + (size_t)e * N;
  const int tid = threadIdx.x;
  const int wave = tid >> 6, lane = tid & 63;
  const int wm = (wave >> 1) << 6, wn = (wave & 1) << 6;
  const int lr = lane & 15, kg = lane >> 4;
  const int col0 = blockIdx.x * 128;
  f32x4 acc[4][4] = {};
  for (int k0 = 0; k0 < K; k0 += 32) {
#pragma unroll
    for (int c = 0; c < 2; c++) {
      int o = c * 4096 + tid * 16;
      int r = o >> 6, cb = (o & 63) >> 1;
      size_t ga = (size_t)(row0 + r) * K + k0 + cb;
      size_t gb = (size_t)(col0 + r) * K + k0 + cb;
      global_to_lds16(Ah + ga, (char*)Ash + o);
      global_to_lds16(Al + ga, (char*)Asl + o);
      global_to_lds16(Bh + gb, (char*)Bsh + o);
      global_to_lds16(Bl + gb, (char*)Bsl + o);
    }
    __syncthreads();
    bf16x8 ah[4], al[4], bh[4], bl[4];
#pragma unroll
    for (int i = 0; i < 4; i++) {
      int ra = (wm + i * 16 + lr) * 32 + kg * 8;
      int rb = (wn + i * 16 + lr) * 32 + kg * 8;
      ah[i] = *(const bf16x8*)&Ash[ra];
      al[i] = *(const bf16x8*)&Asl[ra];
      bh[i] = *(const bf16x8*)&Bsh[rb];
      bl[i] = *(const bf16x8*)&Bsl[rb];
    }
#pragma unroll
    for (int mi = 0; mi < 4; mi++)
#pragma unroll
      for (int ni = 0; ni < 4; ni++) {
        acc[mi][ni] = __builtin_amdgcn_mfma_f32_16x16x32_bf16(ah[mi], bh[ni], acc[mi][ni], 0, 0, 0);
        acc[mi][ni] = __builtin_amdgcn_mfma_f32_16x16x32_bf16(ah[mi], bl[ni], acc[mi][ni], 0, 0, 0);
        acc[mi][ni] = __builtin_amdgcn_mfma_f32_16x16x32_bf16(al[mi], bh[ni], acc[mi][ni], 0, 0, 0);
      }
    __syncthreads();
  }
#pragma unroll
  for (int mi = 0; mi < 4; mi++) {
#pragma unroll
    for (int r = 0; r < 4; r++) {
      int m = row0 + wm + mi * 16 + kg * 4 + r;
      if (m >= rend) continue;
      float* crow = C + (size_t)m * N;
#pragma unroll
      for (int ni = 0; ni < 4; ni++) {
        int n = col0 + wn + ni * 16 + lr;
        crow[n] = acc[mi][ni][r] + bias[n];
      }
    }
  }
}

// ---------------- flash attention: one block = 64 q-rows of one (b,h) ----------------
// Split-bf16 MFMA for QK^T and PV; fp32 online softmax. Causal.
__global__ __launch_bounds__(256) void k_attn(const float* __restrict__ qkv,
    bf16_t* __restrict__ ctxh, bf16_t* __restrict__ ctxl) {
  int blk = blockIdx.x;
  int qt = blk & 15, h = (blk >> 4) & 15, b = blk >> 8;
  int tid = threadIdx.x, wave = tid >> 6, lane = tid & 63;
  int lr = lane & 15, kg = lane >> 4;

  __shared__ __align__(16) bf16_t Ksh[64 * 72], Ksl[64 * 72];
  __shared__ __align__(16) bf16_t Vth[64 * 72], Vtl[64 * 72];
  __shared__ __align__(16) bf16_t Ph[4][16 * 72], Pl[4][16 * 72];

  // Q fragments (A-operand): rows = qt*64 + wave*16 + lr, k = g*32 + kg*8 + j
  int qrow = qt * 64 + wave * 16 + lr;
  const float* qptr = qkv + (size_t)(b * S_ + qrow) * 3072 + h * 64;
  bf16x8 qh[2], ql[2];
#pragma unroll
  for (int g = 0; g < 2; g++) {
    float4 v0 = *(const float4*)(qptr + g * 32 + kg * 8);
    float4 v1 = *(const float4*)(qptr + g * 32 + kg * 8 + 4);
    float f[8] = {v0.x, v0.y, v0.z, v0.w, v1.x, v1.y, v1.z, v1.w};
#pragma unroll
    for (int j = 0; j < 8; j++) {
      float x = f[j] * 0.125f;                 // fold 1/sqrt(64)
      bf16_t hh = (bf16_t)x;
      qh[g][j] = hh;
      ql[g][j] = (bf16_t)(x - (float)hh);
    }
  }

  f32x4 acc[4] = {};                           // O in C-layout: d-tile ni, row kg*4+r
  float mrow[4], lrow[4];
#pragma unroll
  for (int r = 0; r < 4; r++) { mrow[r] = -1e30f; lrow[r] = 0.f; }

  for (int kt = 0; kt <= qt; kt++) {
    __syncthreads();
    // stage K (row-major) and V (transposed) as split bf16; 256 threads cover 64x64
    {
      int row = tid >> 2;
      int c0 = (tid & 3) * 16;
      const float* kr = qkv + (size_t)(b * S_ + kt * 64 + row) * 3072 + 1024 + h * 64 + c0;
      const float* vr = kr + 1024;
#pragma unroll
      for (int cc = 0; cc < 16; cc += 4) {
        float4 kv = *(const float4*)(kr + cc);
        float4 vv = *(const float4*)(vr + cc);
        float kf[4] = {kv.x, kv.y, kv.z, kv.w};
        float vf[4] = {vv.x, vv.y, vv.z, vv.w};
#pragma unroll
        for (int u = 0; u < 4; u++) {
          int c = c0 + cc + u;
          bf16_t hh = (bf16_t)kf[u];
          Ksh[row * 72 + c] = hh;
          Ksl[row * 72 + c] = (bf16_t)(kf[u] - (float)hh);
          bf16_t vh = (bf16_t)vf[u];
          Vth[c * 72 + row] = vh;
          Vtl[c * 72 + row] = (bf16_t)(vf[u] - (float)vh);
        }
      }
    }
    __syncthreads();

    // scores Sc[16q x 64k] per wave (C-layout: col=lr -> k, row=kg*4+r -> q)
    f32x4 sc[4];
#pragma unroll
    for (int ni = 0; ni < 4; ni++) {
      f32x4 s = {};
#pragma unroll
      for (int g = 0; g < 2; g++) {
        int ro = (ni * 16 + lr) * 72 + g * 32 + kg * 8;
        bf16x8 kh = *(const bf16x8*)&Ksh[ro];
        bf16x8 kl = *(const bf16x8*)&Ksl[ro];
        s = __builtin_amdgcn_mfma_f32_16x16x32_bf16(qh[g], kh, s, 0, 0, 0);
        s = __builtin_amdgcn_mfma_f32_16x16x32_bf16(qh[g], kl, s, 0, 0, 0);
        s = __builtin_amdgcn_mfma_f32_16x16x32_bf16(ql[g], kh, s, 0, 0, 0);
      }
      sc[ni] = s;
    }

    int kbase = kt * 64;
    int myrow = qt * 64 + wave * 16 + kg * 4;
    if (kt == qt) {
#pragma unroll
      for (int ni = 0; ni < 4; ni++)
#pragma unroll
        for (int r = 0; r < 4; r++)
          if (kbase + ni * 16 + lr > myrow + r) sc[ni][r] = -1e30f;
    }

    // online softmax update
    float alpha[4];
#pragma unroll
    for (int r = 0; r < 4; r++) {
      float v = fmaxf(fmaxf(sc[0][r], sc[1][r]), fmaxf(sc[2][r], sc[3][r]));
#pragma unroll
      for (int o = 8; o; o >>= 1) v = fmaxf(v, __shfl_xor(v, o, 64));
      float mn = fmaxf(mrow[r], v);
      alpha[r] = __expf(mrow[r] - mn);
      mrow[r] = mn;
    }
    float rsum[4] = {0.f, 0.f, 0.f, 0.f};
#pragma unroll
    for (int ni = 0; ni < 4; ni++) {
#pragma unroll
      for (int r = 0; r < 4; r++) {
        float p = __expf(sc[ni][r] - mrow[r]);
        rsum[r] += p;
        bf16_t ph = (bf16_t)p;
        int po_ = (kg * 4 + r) * 72 + ni * 16 + lr;
        Ph[wave][po_] = ph;
        Pl[wave][po_] = (bf16_t)(p - (float)ph);
      }
    }
#pragma unroll
    for (int r = 0; r < 4; r++) {
      float v = rsum[r];
#pragma unroll
      for (int o = 8; o; o >>= 1) v += __shfl_xor(v, o, 64);
      lrow[r] = lrow[r] * alpha[r] + v;
    }
#pragma unroll
    for (int ni = 0; ni < 4; ni++)
#pragma unroll
      for (int r = 0; r < 4; r++) acc[ni][r] *= alpha[r];

    // PV: read P as A-fragments (same-wave LDS, compiler inserts lgkmcnt)
    bf16x8 pfh[2], pfl[2];
#pragma unroll
    for (int g = 0; g < 2; g++) {
      int po_ = lr * 72 + g * 32 + kg * 8;
      pfh[g] = *(const bf16x8*)&Ph[wave][po_];
      pfl[g] = *(const bf16x8*)&Pl[wave][po_];
    }
#pragma unroll
    for (int ni = 0; ni < 4; ni++) {
#pragma unroll
      for (int g = 0; g < 2; g++) {
        int vo = (ni * 16 + lr) * 72 + g * 32 + kg * 8;
        bf16x8 vh = *(const bf16x8*)&Vth[vo];
        bf16x8 vl = *(const bf16x8*)&Vtl[vo];
        acc[ni] = __builtin_amdgcn_mfma_f32_16x16x32_bf16(pfh[g], vh, acc[ni], 0, 0, 0);
        acc[ni] = __builtin_amdgcn_mfma_f32_16x16x32_bf16(pfh[g], vl, acc[ni], 0, 0, 0);
        acc[ni] = __builtin_amdgcn_mfma_f32_16x16x32_bf16(pfl[g], vh, acc[ni], 0, 0, 0);
      }
    }
  }

  // epilogue: normalize, split, write ctx
  int trow = b * S_ + qt * 64 + wave * 16 + kg * 4;
#pragma unroll
  for (int r = 0; r < 4; r++) {
    float inv = 1.f / lrow[r];
#pragma unroll
    for (int ni = 0; ni < 4; ni++) {
      float x = acc[ni][r] * inv;
      bf16_t hh = (bf16_t)x;
      size_t idx = (size_t)(trow + r) * D_ + h * 64 + ni * 16 + lr;
      ctxh[idx] = hh;
      ctxl[idx] = (bf16_t)(x - (float)hh);
    }
  }
}

// ---------------- gate + grouped top-k routing (one wave per token, fp32 exact) ----------------
__global__ __launch_bounds__(64) void k_route(const float* __restrict__ h2,
    const float* __restrict__ gw, int* __restrict__ eidx, float* __restrict__ ew,
    int* __restrict__ cnt) {
  int t = blockIdx.x, lane = threadIdx.x;
  const float* x = h2 + (size_t)t * D_;
  float lg[8];
#pragma unroll
  for (int e = 0; e < 8; e++) {
    const float* w = gw + e * D_;
    float a = 0.f;
    for (int d = lane; d < D_; d += 64) a += x[d] * w[d];
#pragma unroll
    for (int o = 32; o; o >>= 1) a += __shfl_xor(a, o, 64);
    lg[e] = a;
  }
  if (lane == 0) {
    float mx = lg[0];
    for (int e = 1; e < 8; e++) mx = fmaxf(mx, lg[e]);
    float p[8], sum = 0.f;
    for (int e = 0; e < 8; e++) { p[e] = __expf(lg[e] - mx); sum += p[e]; }
    float inv = 1.f / sum;
    for (int e = 0; e < 8; e++) p[e] *= inv;
    float gs[4];
    for (int gi = 0; gi < 4; gi++) gs[gi] = fmaxf(p[2 * gi], p[2 * gi + 1]);
    int g0 = 0;
    for (int gi = 1; gi < 4; gi++) if (gs[gi] > gs[g0]) g0 = gi;
    int g1 = -1;
    for (int gi = 0; gi < 4; gi++) {
      if (gi == g0) continue;
      if (g1 < 0 || gs[gi] > gs[g1]) g1 = gi;
    }
    int i0 = -1, i1 = -1; float v0 = -1.f, v1 = -1.f;
    for (int e = 0; e < 8; e++) {
      int gi = e >> 1;
      if (gi != g0 && gi != g1) continue;
      if (p[e] > v0) { v1 = v0; i1 = i0; v0 = p[e]; i0 = e; }
      else if (p[e] > v1) { v1 = p[e]; i1 = e; }
    }
    eidx[2 * t] = i0; eidx[2 * t + 1] = i1;
    ew[2 * t] = v0; ew[2 * t + 1] = v1;
    atomicAdd(&cnt[i0], 1);
    atomicAdd(&cnt[i1], 1);
  }
}

// ---------------- expert offsets + tile table (128-aligned segments) ----------------
__global__ void k_offsets(const int* __restrict__ cnt, int* __restrict__ poff,
                          int* __restrict__ te, int* __restrict__ tr0,
                          int* __restrict__ trend, int* __restrict__ ntl) {
  if (threadIdx.x != 0 || blockIdx.x != 0) return;
  int offv = 0, nt = 0;
  for (int e = 0; e < 8; e++) {
    poff[e] = offv;
    int c = cnt[e];
    int ntile = (c + 127) >> 7;
    for (int i = 0; i < ntile; i++) {
      te[nt] = e; tr0[nt] = offv + i * 128; trend[nt] = offv + c; nt++;
    }
    offv += ntile << 7;
  }
  poff[8] = offv;
  *ntl = nt;
}

__global__ __launch_bounds__(256) void k_fill(const int* __restrict__ eidx,
    const int* __restrict__ poff,
    int* __restrict__ cur, int* __restrict__ rowtok, int* __restrict__ postk) {
  int t = blockIdx.x * 256 + threadIdx.x;
  if (t >= T_) return;
#pragma unroll
  for (int k = 0; k < 2; k++) {
    int e = eidx[2 * t + k];
    int r = atomicAdd(&cur[e], 1);
    int pos = poff[e] + r;
    rowtok[pos] = t;
    postk[2 * t + k] = pos;
  }
}

__global__ __launch_bounds__(256) void k_gather(const int* __restrict__ rowtok,
    const bf16_t* __restrict__ h2h, const bf16_t* __restrict__ h2l,
    bf16_t* __restrict__ amh, bf16_t* __restrict__ aml) {
  int rrow = blockIdx.x;
  int tid = threadIdx.x;
  int t = rowtok[rrow];
  ushort4* dh = (ushort4*)(amh + (size_t)rrow * D_);
  ushort4* dl = (ushort4*)(aml + (size_t)rrow * D_);
  if (t < 0) {
    dh[tid] = make_ushort4(0, 0, 0, 0);
    dl[tid] = make_ushort4(0, 0, 0, 0);
  } else {
    dh[tid] = ((const ushort4*)(h2h + (size_t)t * D_))[tid];
    dl[tid] = ((const ushort4*)(h2l + (size_t)t * D_))[tid];
  }
}

// fused swiglu: h13[row][2048] -> act[row][1024] (split)
__global__ __launch_bounds__(256) void k_swiglu2(const float* __restrict__ h13,
    bf16_t* __restrict__ acth, bf16_t* __restrict__ actl) {
  int row = blockIdx.x, tid = threadIdx.x;
  const float4* hr = (const float4*)(h13 + (size_t)row * 2048);
  float4 a = hr[tid];
  float4 c = hr[256 + tid];
  float4 o;
  o.x = a.x / (1.f + __expf(-a.x)) * c.x;
  o.y = a.y / (1.f + __expf(-a.y)) * c.y;
  o.z = a.z / (1.f + __expf(-a.z)) * c.z;
  o.w = a.w / (1.f + __expf(-a.w)) * c.w;
  union { bf16_t h[4]; ushort4 u; } ch, cl;
  split2(o.x, ch.h[0], cl.h[0]);
  split2(o.y, ch.h[1], cl.h[1]);
  split2(o.z, ch.h[2], cl.h[2]);
  split2(o.w, ch.h[3], cl.h[3]);
  ((ushort4*)acth)[(size_t)row * 256 + tid] = ch.u;
  ((ushort4*)actl)[(size_t)row * 256 + tid] = cl.u;
}

__global__ __launch_bounds__(256) void k_scatter(const float* __restrict__ outm,
    const int* __restrict__ postk, const float* __restrict__ ewt,
    float* __restrict__ y) {
  int t = blockIdx.x, tid = threadIdx.x;
  int p0 = postk[2 * t], p1 = postk[2 * t + 1];
  float w0 = ewt[2 * t], w1 = ewt[2 * t + 1];
  float4* yr = (float4*)(y + (size_t)t * D_);
  const float4* a = (const float4*)(outm + (size_t)p0 * D_);
  const float4* b = (const float4*)(outm + (size_t)p1 * D_);
  float4 v = yr[tid], va = a[tid], vb = b[tid];
  v.x += w0 * va.x + w1 * vb.x;
  v.y += w0 * va.y + w1 * vb.y;
  v.z += w0 * va.z + w1 * vb.z;
  v.w += w0 * va.w + w1 * vb.w;
  yr[tid] = v;
}

extern "C" void kernel_launch(void* const* d_in, const int* in_sizes, int n_in,
                              void* d_out, int out_size, void* d_ws, size_t ws_size,
                              hipStream_t stream) {
  const float* src  = (const float*)d_in[0];
  const float* qkvw = (const float*)d_in[1];
  const float* qkvb = (const float*)d_in[2];
  const float* outw = (const float*)d_in[3];
  const float* outb = (const float*)d_in[4];
  const float* n1g  = (const float*)d_in[5];
  const float* n1b  = (const float*)d_in[6];
  const float* n2g  = (const float*)d_in[7];
  const float* n2b  = (const float*)d_in[8];
  const float* gw   = (const float*)d_in[9];
  const float* ew1  = (const float*)d_in[10];
  const float* eb1  = (const float*)d_in[11];
  const float* ew2  = (const float*)d_in[12];
  const float* eb2  = (const float*)d_in[13];
  const float* ew3  = (const float*)d_in[14];
  const float* eb3  = (const float*)d_in[15];
  const float* sw1  = (const float*)d_in[16];
  const float* sb1  = (const float*)d_in[17];
  const float* sw2  = (const float*)d_in[18];
  const float* sb2  = (const float*)d_in[19];
  const float* sw3  = (const float*)d_in[20];
  const float* sb3  = (const float*)d_in[21];
  const float* fng  = (const float*)d_in[22];
  const float* fnb  = (const float*)d_in[23];
  float* outp = (float*)d_out;

  char* base = (char*)d_ws;
  size_t off = 0;
  auto alloc = [&](size_t bytes) -> void* {
    off = (off + 255) & ~(size_t)255;
    void* r = base + off;
    off += bytes;
    return r;
  };
  bf16_t* wqkv_h  = (bf16_t*)alloc((size_t)3072 * 1024 * 2);
  bf16_t* wqkv_l  = (bf16_t*)alloc((size_t)3072 * 1024 * 2);
  bf16_t* wout_h  = (bf16_t*)alloc((size_t)1024 * 1024 * 2);
  bf16_t* wout_l  = (bf16_t*)alloc((size_t)1024 * 1024 * 2);
  bf16_t* we13_h  = (bf16_t*)alloc((size_t)16 * 1024 * 1024 * 2);  // [e][2048][1024]
  bf16_t* we13_l  = (bf16_t*)alloc((size_t)16 * 1024 * 1024 * 2);
  bf16_t* we2_h   = (bf16_t*)alloc((size_t)8 * 1024 * 1024 * 2);
  bf16_t* we2_l   = (bf16_t*)alloc((size_t)8 * 1024 * 1024 * 2);
  bf16_t* wsh13_h = (bf16_t*)alloc((size_t)2 * 1024 * 1024 * 2);   // [2048][1024]
  bf16_t* wsh13_l = (bf16_t*)alloc((size_t)2 * 1024 * 1024 * 2);
  bf16_t* wsh2_h  = (bf16_t*)alloc((size_t)1024 * 1024 * 2);
  bf16_t* wsh2_l  = (bf16_t*)alloc((size_t)1024 * 1024 * 2);
  float*  ebc13   = (float*)alloc((size_t)8 * 2048 * 4);
  float*  sbc13   = (float*)alloc((size_t)2048 * 4);
  float*  y    = (float*)alloc((size_t)T_ * D_ * 4);
  float*  lnf  = (float*)alloc((size_t)T_ * D_ * 4);
  bf16_t* lnb_h = (bf16_t*)alloc((size_t)T_ * D_ * 2);
  bf16_t* lnb_l = (bf16_t*)alloc((size_t)T_ * D_ * 2);
  bf16_t* ctx_h = (bf16_t*)alloc((size_t)T_ * D_ * 2);
  bf16_t* ctx_l = (bf16_t*)alloc((size_t)T_ * D_ * 2);
  // regA union: qkvbuf (25MB) / h13m (42MB) / outm (21MB) / h13s (17MB)
  char* regA   = (char*)alloc((size_t)MOE_ROWS * 2048 * 4);
  float* qkvbuf = (float*)regA;
  float* h13m   = (float*)regA;
  float* outm   = (float*)regA;
  float* h13s   = (float*)regA;
  // regU: act planes + gathered-A planes
  char* regU = (char*)alloc((size_t)4 * MOE_ROWS * 1024 * 2);
  bf16_t* act_h  = (bf16_t*)regU;
  bf16_t* act_l  = (bf16_t*)(regU + (size_t)MOE_ROWS * 1024 * 2);
  bf16_t* amoe_h = (bf16_t*)(regU + (size_t)2 * MOE_ROWS * 1024 * 2);
  bf16_t* amoe_l = (bf16_t*)(regU + (size_t)3 * MOE_ROWS * 1024 * 2);
  int*   eidx = (int*)alloc((size_t)T_ * 2 * 4);
  float* ewt  = (float*)alloc((size_t)T_ * 2 * 4);
  int* cnt  = (int*)alloc(64);
  int* cur  = (int*)alloc(64);
  int* poff = (int*)alloc(64);
  int* te   = (int*)alloc(256);
  int* tr0  = (int*)alloc(256);
  int* trend = (int*)alloc(256);
  int* ntl  = (int*)alloc(16);
  int* rowtok = (int*)alloc((size_t)MOE_ROWS * 4);
  int* postk  = (int*)alloc((size_t)T_ * 2 * 4);
  (void)ws_size; (void)in_sizes; (void)n_in; (void)out_size;

  (void)hipMemcpyAsync(y, src, (size_t)T_ * D_ * 4, hipMemcpyDeviceToDevice, stream);

  for (int l = 0; l < 2; l++) {
    size_t lf = (size_t)l;
    // weight conversion (fp32 -> hi/lo bf16 planes), fused w1||w3 layouts
    k_cvt2<<<3072, 256, 0, stream>>>(qkvw + lf * 3145728, wqkv_h, wqkv_l, 3145728);
    k_cvt2<<<1024, 256, 0, stream>>>(outw + lf * 1048576, wout_h, wout_l, 1048576);
    k_cvt2s<<<8192, 256, 0, stream>>>(ew1 + lf * 8388608, we13_h, we13_l, 8388608, 0);
    k_cvt2s<<<8192, 256, 0, stream>>>(ew3 + lf * 8388608, we13_h, we13_l, 8388608, 1048576);
    k_cvt2<<<8192, 256, 0, stream>>>(ew2 + lf * 8388608, we2_h, we2_l, 8388608);
    k_cvt2<<<1024, 256, 0, stream>>>(sw1 + lf * 1048576, wsh13_h, wsh13_l, 1048576);
    k_cvt2<<<1024, 256, 0, stream>>>(sw3 + lf * 1048576, wsh13_h + 1048576, wsh13_l + 1048576, 1048576);
    k_cvt2<<<1024, 256, 0, stream>>>(sw2 + lf * 1048576, wsh2_h, wsh2_l, 1048576);
    k_catbias_e<<<64, 256, 0, stream>>>(eb1 + lf * 8192, eb3 + lf * 8192, ebc13);
    k_catbias_s<<<8, 256, 0, stream>>>(sb1 + lf * 1024, sb3 + lf * 1024, sbc13);

    // LN1 -> split bf16
    k_ln<<<T_, 256, 0, stream>>>(y, n1g + lf * 1024, n1b + lf * 1024,
                                 (float*)nullptr, lnb_h, lnb_l);
    // QKV projection
    k_gemm<<<dim3(24, 16), 256, 0, stream>>>(lnb_h, lnb_l, wqkv_h, wqkv_l, qkvbuf,
                                             qkvb + lf * 3072, T_, 3072, 1024, 0);
    // flash attention -> ctx (split)
    k_attn<<<512, 256, 0, stream>>>(qkvbuf, ctx_h, ctx_l);
    // out projection, residual-add into y
    k_gemm<<<dim3(8, 16), 256, 0, stream>>>(ctx_h, ctx_l, wout_h, wout_l, y,
                                            outb + lf * 1024, T_, 1024, 1024, 1);
    // LN2 -> f32 + split bf16
    k_ln<<<T_, 256, 0, stream>>>(y, n2g + lf * 1024, n2b + lf * 1024, lnf, lnb_h, lnb_l);

    // routing (fp32 exact)
    (void)hipMemsetAsync(cnt, 0, 64, stream);
    (void)hipMemsetAsync(cur, 0, 64, stream);
    (void)hipMemsetAsync(rowtok, 0xFF, (size_t)MOE_ROWS * 4, stream);
    k_route<<<T_, 64, 0, stream>>>(lnf, gw + lf * 8192, eidx, ewt, cnt);
    k_offsets<<<1, 1, 0, stream>>>(cnt, poff, te, tr0, trend, ntl);
    k_fill<<<8, 256, 0, stream>>>(eidx, poff, cur, rowtok, postk);
    k_gather<<<MOE_ROWS, 256, 0, stream>>>(rowtok, lnb_h, lnb_l, amoe_h, amoe_l);

    // routed experts: fused up (w1||w3), swiglu, down
    k_gemm_grp<<<dim3(16, MAX_TILES), 256, 0, stream>>>(amoe_h, amoe_l, we13_h, we13_l,
        h13m, ebc13, te, tr0, trend, ntl, 2048, 1024);
    k_swiglu2<<<MOE_ROWS, 256, 0, stream>>>(h13m, act_h, act_l);
    k_gemm_grp<<<dim3(8, MAX_TILES), 256, 0, stream>>>(act_h, act_l, we2_h, we2_l, outm,
        eb2 + lf * 8192, te, tr0, trend, ntl, 1024, 1024);
    k_scatter<<<T_, 256, 0, stream>>>(outm, postk, ewt, y);

    // shared expert: fused up, swiglu, down (regA free after scatter)
    k_gemm<<<dim3(16, 16), 256, 0, stream>>>(lnb_h, lnb_l, wsh13_h, wsh13_l, h13s,
                                             sbc13, T_, 2048, 1024, 0);
    k_swiglu2<<<T_, 256, 0, stream>>>(h13s, act_h, act_l);
    k_gemm<<<dim3(8, 16), 256, 0, stream>>>(act_h, act_l, wsh2_h, wsh2_l, y,
                                            sb2 + lf * 1024, T_, 1024, 1024, 1);
  }

  k_ln<<<T_, 256, 0, stream>>>(y, fng, fnb, outp, (bf16_t*)nullptr, (bf16_t*)nullptr);
}

// Round 5
// 1331.318 us; speedup vs baseline: 1.6968x; 1.2109x over previous
//
#include <hip/hip_runtime.h>
#include <cstdint>
#include <cstddef>

typedef __bf16 bf16_t;
typedef __attribute__((ext_vector_type(8))) __bf16 bf16x8;
typedef __attribute__((ext_vector_type(4))) float f32x4;

#define B_ 2
#define S_ 1024
#define D_ 1024
#define H_ 16
#define T_ 2048
#define E_ 8
#define F_ 1024
#define RT_ROWS 5120          // routed region (128-padded)
#define ALL_ROWS 7168         // + shared segment [5120,7168)
#define MAX_TILES 56          // <=40 routed + 16 shared

// ---------------- async global->LDS (16B per lane) ----------------
__device__ __forceinline__ void global_to_lds16(const void* g, void* l) {
  __builtin_amdgcn_global_load_lds(
      (__attribute__((address_space(1))) unsigned int*)(uintptr_t)g,
      (__attribute__((address_space(3))) unsigned int*)(unsigned int)(uintptr_t)l,
      16, 0, 0);
}

// ---------------- fp32 -> split bf16 (hi, lo) ----------------
__device__ __forceinline__ void split2(float x, bf16_t& h, bf16_t& l) {
  h = (bf16_t)x;
  l = (bf16_t)(x - (float)h);
}

__device__ __forceinline__ void cvt4(const float* __restrict__ s, size_t si,
                                     bf16_t* __restrict__ dh, bf16_t* __restrict__ dl,
                                     size_t di) {
  float4 v = *(const float4*)(s + si);
  union { bf16_t h[4]; ushort4 u; } ch, cl;
  split2(v.x, ch.h[0], cl.h[0]);
  split2(v.y, ch.h[1], cl.h[1]);
  split2(v.z, ch.h[2], cl.h[2]);
  split2(v.w, ch.h[3], cl.h[3]);
  *(ushort4*)(dh + di) = ch.u;
  *(ushort4*)(dl + di) = cl.u;
}

// one kernel converts ALL weights of a layer into hi/lo planes.
// we13 layout: [e][2048][1024], expert row 2j = w1 row j, row 2j+1 = w3 row j (interleaved).
// block ranges (1024 elems per block):
//  [0,3072) qkv | [3072,4096) wout | [4096,12288) e1 | [12288,20480) e3
//  [20480,28672) e2 | [28672,29696) sw1 | [29696,30720) sw3 | [30720,31744) sw2
__global__ __launch_bounds__(256) void k_cvtall(
    const float* __restrict__ qkvw, const float* __restrict__ outw,
    const float* __restrict__ ew1, const float* __restrict__ ew3,
    const float* __restrict__ ew2, const float* __restrict__ sw1,
    const float* __restrict__ sw3, const float* __restrict__ sw2,
    bf16_t* __restrict__ wqkv_h, bf16_t* __restrict__ wqkv_l,
    bf16_t* __restrict__ wout_h, bf16_t* __restrict__ wout_l,
    bf16_t* __restrict__ we13_h, bf16_t* __restrict__ we13_l,
    bf16_t* __restrict__ we2_h,  bf16_t* __restrict__ we2_l,
    int* __restrict__ cnt, int* __restrict__ cur) {
  int blk = blockIdx.x;
  if (blk == 0 && threadIdx.x < 16) {
    if (threadIdx.x < 8) cnt[threadIdx.x] = 0;
    else cur[threadIdx.x - 8] = 0;
  }
  if (blk < 3072) {
    size_t i = (size_t)blk * 1024 + threadIdx.x * 4;
    cvt4(qkvw, i, wqkv_h, wqkv_l, i);
  } else if (blk < 4096) {
    size_t i = (size_t)(blk - 3072) * 1024 + threadIdx.x * 4;
    cvt4(outw, i, wout_h, wout_l, i);
  } else if (blk < 12288) {
    size_t i = (size_t)(blk - 4096) * 1024 + threadIdx.x * 4;
    size_t e = i >> 20, r = i & 1048575;
    cvt4(ew1, i, we13_h, we13_l, e * 2097152 + ((r >> 10) << 11) + (r & 1023));
  } else if (blk < 20480) {
    size_t i = (size_t)(blk - 12288) * 1024 + threadIdx.x * 4;
    size_t e = i >> 20, r = i & 1048575;
    cvt4(ew3, i, we13_h, we13_l, e * 2097152 + ((r >> 10) << 11) + 1024 + (r & 1023));
  } else if (blk < 28672) {
    size_t i = (size_t)(blk - 20480) * 1024 + threadIdx.x * 4;
    cvt4(ew2, i, we2_h, we2_l, i);
  } else if (blk < 29696) {
    size_t i = (size_t)(blk - 28672) * 1024 + threadIdx.x * 4;
    cvt4(sw1, i, we13_h, we13_l, (size_t)8 * 2097152 + ((i >> 10) << 11) + (i & 1023));
  } else if (blk < 30720) {
    size_t i = (size_t)(blk - 29696) * 1024 + threadIdx.x * 4;
    cvt4(sw3, i, we13_h, we13_l, (size_t)8 * 2097152 + ((i >> 10) << 11) + 1024 + (i & 1023));
  } else {
    size_t i = (size_t)(blk - 30720) * 1024 + threadIdx.x * 4;
    cvt4(sw2, i, we2_h, we2_l, (size_t)8 * 1048576 + i);
  }
}

// bias tables: ebc13[9][2048] interleaved (col 2j=b1[j], 2j+1=b3[j]; e8=shared), eb2c[9][1024]
__global__ __launch_bounds__(256) void k_catbias(const float* __restrict__ eb1,
    const float* __restrict__ eb3, const float* __restrict__ sb1,
    const float* __restrict__ sb3, const float* __restrict__ eb2,
    const float* __restrict__ sb2, float* __restrict__ ebc13,
    float* __restrict__ eb2c) {
  int i = blockIdx.x * 256 + threadIdx.x;
  if (i < 9 * 2048) {
    int e = i >> 11, c = i & 2047, j = c >> 1;
    float v;
    if (e < 8) v = ((c & 1) == 0) ? eb1[e * 1024 + j] : eb3[e * 1024 + j];
    else       v = ((c & 1) == 0) ? sb1[j] : sb3[j];
    ebc13[i] = v;
  } else {
    int k = i - 9 * 2048;
    if (k < 9 * 1024) {
      int e = k >> 10, j = k & 1023;
      eb2c[k] = (e < 8) ? eb2[e * 1024 + j] : sb2[j];
    }
  }
}

// ---------------- LayerNorm (one block per row of 1024) ----------------
__global__ __launch_bounds__(256) void k_ln(const float* __restrict__ x,
    const float* __restrict__ g, const float* __restrict__ b,
    float* __restrict__ of, bf16_t* __restrict__ obh, bf16_t* __restrict__ obl) {
  int t = blockIdx.x, tid = threadIdx.x;
  const float4* xr = (const float4*)(x + (size_t)t * D_);
  float4 v = xr[tid];
  float s = v.x + v.y + v.z + v.w;
  float s2 = v.x * v.x + v.y * v.y + v.z * v.z + v.w * v.w;
#pragma unroll
  for (int o = 32; o; o >>= 1) { s += __shfl_xor(s, o, 64); s2 += __shfl_xor(s2, o, 64); }
  __shared__ float rs[4], rs2[4];
  if ((tid & 63) == 0) { rs[tid >> 6] = s; rs2[tid >> 6] = s2; }
  __syncthreads();
  s = rs[0] + rs[1] + rs[2] + rs[3];
  s2 = rs2[0] + rs2[1] + rs2[2] + rs2[3];
  float mu = s * (1.f / D_);
  float var = s2 * (1.f / D_) - mu * mu;
  float r = rsqrtf(var + 1e-5f);
  float4 gg = ((const float4*)g)[tid];
  float4 bb = ((const float4*)b)[tid];
  float4 o;
  o.x = (v.x - mu) * r * gg.x + bb.x;
  o.y = (v.y - mu) * r * gg.y + bb.y;
  o.z = (v.z - mu) * r * gg.z + bb.z;
  o.w = (v.w - mu) * r * gg.w + bb.w;
  if (of) ((float4*)(of + (size_t)t * D_))[tid] = o;
  if (obh) {
    union { bf16_t h[4]; ushort4 u; } ch, cl;
    split2(o.x, ch.h[0], cl.h[0]);
    split2(o.y, ch.h[1], cl.h[1]);
    split2(o.z, ch.h[2], cl.h[2]);
    split2(o.w, ch.h[3], cl.h[3]);
    *(ushort4*)(obh + (size_t)t * D_ + tid * 4) = ch.u;
    *(ushort4*)(obl + (size_t)t * D_ + tid * 4) = cl.u;
  }
}

// ---- split-precision GEMM: C[M,N] (+)= A[M,K] @ B[N,K]^T + bias ----
__global__ __launch_bounds__(256) void k_gemm(const bf16_t* __restrict__ Ah,
    const bf16_t* __restrict__ Al, const bf16_t* __restrict__ Bh,
    const bf16_t* __restrict__ Bl, float* __restrict__ C,
    const float* __restrict__ bias, int M, int N, int K, int addC) {
  __shared__ __align__(16) bf16_t Ash[128 * 32];
  __shared__ __align__(16) bf16_t Asl[128 * 32];
  __shared__ __align__(16) bf16_t Bsh[128 * 32];
  __shared__ __align__(16) bf16_t Bsl[128 * 32];
  const int tid = threadIdx.x;
  const int wave = tid >> 6, lane = tid & 63;
  const int wm = (wave >> 1) << 6, wn = (wave & 1) << 6;
  const int lr = lane & 15, kg = lane >> 4;
  const int row0 = blockIdx.y * 128, col0 = blockIdx.x * 128;
  f32x4 acc[4][4] = {};
  for (int k0 = 0; k0 < K; k0 += 32) {
#pragma unroll
    for (int c = 0; c < 2; c++) {
      int o = c * 4096 + tid * 16;
      int r = o >> 6, cb = (o & 63) >> 1;
      size_t ga = (size_t)(row0 + r) * K + k0 + cb;
      size_t gb = (size_t)(col0 + r) * K + k0 + cb;
      global_to_lds16(Ah + ga, (char*)Ash + o);
      global_to_lds16(Al + ga, (char*)Asl + o);
      global_to_lds16(Bh + gb, (char*)Bsh + o);
      global_to_lds16(Bl + gb, (char*)Bsl + o);
    }
    __syncthreads();
    bf16x8 ah[4], al[4], bh[4], bl[4];
#pragma unroll
    for (int i = 0; i < 4; i++) {
      int ra = (wm + i * 16 + lr) * 32 + kg * 8;
      int rb = (wn + i * 16 + lr) * 32 + kg * 8;
      ah[i] = *(const bf16x8*)&Ash[ra];
      al[i] = *(const bf16x8*)&Asl[ra];
      bh[i] = *(const bf16x8*)&Bsh[rb];
      bl[i] = *(const bf16x8*)&Bsl[rb];
    }
#pragma unroll
    for (int mi = 0; mi < 4; mi++)
#pragma unroll
      for (int ni = 0; ni < 4; ni++) {
        acc[mi][ni] = __builtin_amdgcn_mfma_f32_16x16x32_bf16(ah[mi], bh[ni], acc[mi][ni], 0, 0, 0);
        acc[mi][ni] = __builtin_amdgcn_mfma_f32_16x16x32_bf16(ah[mi], bl[ni], acc[mi][ni], 0, 0, 0);
        acc[mi][ni] = __builtin_amdgcn_mfma_f32_16x16x32_bf16(al[mi], bh[ni], acc[mi][ni], 0, 0, 0);
      }
    __syncthreads();
  }
#pragma unroll
  for (int mi = 0; mi < 4; mi++) {
#pragma unroll
    for (int r = 0; r < 4; r++) {
      int m = row0 + wm + mi * 16 + kg * 4 + r;
      if (m >= M) continue;
      float* crow = C + (size_t)m * N;
#pragma unroll
      for (int ni = 0; ni < 4; ni++) {
        int n = col0 + wn + ni * 16 + lr;
        float v = acc[mi][ni][r];
        if (bias) v += bias[n];
        if (addC) crow[n] += v; else crow[n] = v;
      }
    }
  }
}

// ---------------- grouped up-GEMM (N=2048,K=1024) + fused SwiGLU epilogue ----------------
// B rows interleaved (2j=w1j, 2j+1=w3j). Epilogue pairs adjacent lanes via shfl_xor(1):
// even lane computes silu(h1)*h3 -> act[m][col/2] (split bf16).
__global__ __launch_bounds__(256) void k_gemm_up(const bf16_t* __restrict__ Ah,
    const bf16_t* __restrict__ Al, const bf16_t* __restrict__ Sh,
    const bf16_t* __restrict__ Sl, const bf16_t* __restrict__ Bbh,
    const bf16_t* __restrict__ Bbl, bf16_t* __restrict__ acth,
    bf16_t* __restrict__ actl, const float* __restrict__ biasbase,
    const int* __restrict__ tile_e, const int* __restrict__ tile_r0,
    const int* __restrict__ tile_rend, const int* __restrict__ ntl) {
  __shared__ __align__(16) bf16_t Ash[128 * 32];
  __shared__ __align__(16) bf16_t Asl[128 * 32];
  __shared__ __align__(16) bf16_t Bsh[128 * 32];
  __shared__ __align__(16) bf16_t Bsl[128 * 32];
  const int K = 1024;
  int ti = blockIdx.y;
  if (ti >= *ntl) return;
  const int e = tile_e[ti];
  const int row0 = tile_r0[ti];
  const int rend = tile_rend[ti];
  const bf16_t* Abh = (e < 8) ? Ah + (size_t)row0 * K : Sh + (size_t)(row0 - RT_ROWS) * K;
  const bf16_t* Abl = (e < 8) ? Al + (size_t)row0 * K : Sl + (size_t)(row0 - RT_ROWS) * K;
  const bf16_t* Bh = Bbh + (size_t)e * 2048 * K;
  const bf16_t* Bl = Bbl + (size_t)e * 2048 * K;
  const float* bias = biasbase + (size_t)e * 2048;
  const int tid = threadIdx.x;
  const int wave = tid >> 6, lane = tid & 63;
  const int wm = (wave >> 1) << 6, wn = (wave & 1) << 6;
  const int lr = lane & 15, kg = lane >> 4;
  const int col0 = blockIdx.x * 128;
  f32x4 acc[4][4] = {};
  for (int k0 = 0; k0 < K; k0 += 32) {
#pragma unroll
    for (int c = 0; c < 2; c++) {
      int o = c * 4096 + tid * 16;
      int r = o >> 6, cb = (o & 63) >> 1;
      size_t ga = (size_t)r * K + k0 + cb;
      size_t gb = (size_t)(col0 + r) * K + k0 + cb;
      global_to_lds16(Abh + ga, (char*)Ash + o);
      global_to_lds16(Abl + ga, (char*)Asl + o);
      global_to_lds16(Bh + gb, (char*)Bsh + o);
      global_to_lds16(Bl + gb, (char*)Bsl + o);
    }
    __syncthreads();
    bf16x8 ah[4], al[4], bh[4], bl[4];
#pragma unroll
    for (int i = 0; i < 4; i++) {
      int ra = (wm + i * 16 + lr) * 32 + kg * 8;
      int rb = (wn + i * 16 + lr) * 32 + kg * 8;
      ah[i] = *(const bf16x8*)&Ash[ra];
      al[i] = *(const bf16x8*)&Asl[ra];
      bh[i] = *(const bf16x8*)&Bsh[rb];
      bl[i] = *(const bf16x8*)&Bsl[rb];
    }
#pragma unroll
    for (int mi = 0; mi < 4; mi++)
#pragma unroll
      for (int ni = 0; ni < 4; ni++) {
        acc[mi][ni] = __builtin_amdgcn_mfma_f32_16x16x32_bf16(ah[mi], bh[ni], acc[mi][ni], 0, 0, 0);
        acc[mi][ni] = __builtin_amdgcn_mfma_f32_16x16x32_bf16(ah[mi], bl[ni], acc[mi][ni], 0, 0, 0);
        acc[mi][ni] = __builtin_amdgcn_mfma_f32_16x16x32_bf16(al[mi], bh[ni], acc[mi][ni], 0, 0, 0);
      }
    __syncthreads();
  }
#pragma unroll
  for (int mi = 0; mi < 4; mi++) {
#pragma unroll
    for (int r = 0; r < 4; r++) {
      int m = row0 + wm + mi * 16 + kg * 4 + r;
      bool ok = (m < rend);
#pragma unroll
      for (int ni = 0; ni < 4; ni++) {
        int col = col0 + wn + ni * 16 + lr;
        float v = acc[mi][ni][r] + bias[col];
        float p = __shfl_xor(v, 1, 64);      // partner column (w3 if lane even)
        if (ok && !(lane & 1)) {
          float o = v / (1.f + __expf(-v)) * p;
          bf16_t hh, ll;
          split2(o, hh, ll);
          size_t di = (size_t)m * 1024 + (col >> 1);
          acth[di] = hh;
          actl[di] = ll;
        }
      }
    }
  }
}

// ---------------- grouped down-GEMM over expert tiles ----------------
__global__ __launch_bounds__(256) void k_gemm_grp(const bf16_t* __restrict__ Ah,
    const bf16_t* __restrict__ Al, const bf16_t* __restrict__ Bbh,
    const bf16_t* __restrict__ Bbl, float* __restrict__ C,
    const float* __restrict__ biasbase,
    const int* __restrict__ tile_e, const int* __restrict__ tile_r0,
    const int* __restrict__ tile_rend, const int* __restrict__ ntl,
    int N, int K) {
  __shared__ __align__(16) bf16_t Ash[128 * 32];
  __shared__ __align__(16) bf16_t Asl[128 * 32];
  __shared__ __align__(16) bf16_t Bsh[128 * 32];
  __shared__ __align__(16) bf16_t Bsl[128 * 32];
  int ti = blockIdx.y;
  if (ti >= *ntl) return;
  const int e = tile_e[ti];
  const int row0 = tile_r0[ti];
  const int rend = tile_rend[ti];
  const bf16_t* Bh = Bbh + (size_t)e * N * K;
  const bf16_t* Bl = Bbl + (size_t)e * N * K;
  const float* bias = biasbase + (size_t)e * N;
  const int tid = threadIdx.x;
  const int wave = tid >> 6, lane = tid & 63;
  const int wm = (wave >> 1) << 6, wn = (wave & 1) << 6;
  const int lr = lane & 15, kg = lane >> 4;
  const int col0 = blockIdx.x * 128;
  f32x4 acc[4][4] = {};
  for (int k0 = 0; k0 < K; k0 += 32) {
#pragma unroll
    for (int c = 0; c < 2; c++) {
      int o = c * 4096 + tid * 16;
      int r = o >> 6, cb = (o & 63) >> 1;
      size_t ga = (size_t)(row0 + r) * K + k0 + cb;
      size_t gb = (size_t)(col0 + r) * K + k0 + cb;
      global_to_lds16(Ah + ga, (char*)Ash + o);
      global_to_lds16(Al + ga, (char*)Asl + o);
      global_to_lds16(Bh + gb, (char*)Bsh + o);
      global_to_lds16(Bl + gb, (char*)Bsl + o);
    }
    __syncthreads();
    bf16x8 ah[4], al[4], bh[4], bl[4];
#pragma unroll
    for (int i = 0; i < 4; i++) {
      int ra = (wm + i * 16 + lr) * 32 + kg * 8;
      int rb = (wn + i * 16 + lr) * 32 + kg * 8;
      ah[i] = *(const bf16x8*)&Ash[ra];
      al[i] = *(const bf16x8*)&Asl[ra];
      bh[i] = *(const bf16x8*)&Bsh[rb];
      bl[i] = *(const bf16x8*)&Bsl[rb];
    }
#pragma unroll
    for (int mi = 0; mi < 4; mi++)
#pragma unroll
      for (int ni = 0; ni < 4; ni++) {
        acc[mi][ni] = __builtin_amdgcn_mfma_f32_16x16x32_bf16(ah[mi], bh[ni], acc[mi][ni], 0, 0, 0);
        acc[mi][ni] = __builtin_amdgcn_mfma_f32_16x16x32_bf16(ah[mi], bl[ni], acc[mi][ni], 0, 0, 0);
        acc[mi][ni] = __builtin_amdgcn_mfma_f32_16x16x32_bf16(al[mi], bh[ni], acc[mi][ni], 0, 0, 0);
      }
    __syncthreads();
  }
#pragma unroll
  for (int mi = 0; mi < 4; mi++) {
#pragma unroll
    for (int r = 0; r < 4; r++) {
      int m = row0 + wm + mi * 16 + kg * 4 + r;
      if (m >= rend) continue;
      float* crow = C + (size_t)m * N;
#pragma unroll
      for (int ni = 0; ni < 4; ni++) {
        int n = col0 + wn + ni * 16 + lr;
        crow[n] = acc[mi][ni][r] + bias[n];
      }
    }
  }
}

// ---------------- flash attention: one block = 64 q-rows of one (b,h) ----------------
__global__ __launch_bounds__(256) void k_attn(const float* __restrict__ qkv,
    bf16_t* __restrict__ ctxh, bf16_t* __restrict__ ctxl) {
  int blk = blockIdx.x;
  int qt = blk & 15, h = (blk >> 4) & 15, b = blk >> 8;
  int tid = threadIdx.x, wave = tid >> 6, lane = tid & 63;
  int lr = lane & 15, kg = lane >> 4;

  __shared__ __align__(16) bf16_t Ksh[64 * 72], Ksl[64 * 72];
  __shared__ __align__(16) bf16_t Vth[64 * 72], Vtl[64 * 72];
  __shared__ __align__(16) bf16_t Ph[4][16 * 72], Pl[4][16 * 72];

  int qrow = qt * 64 + wave * 16 + lr;
  const float* qptr = qkv + (size_t)(b * S_ + qrow) * 3072 + h * 64;
  bf16x8 qh[2], ql[2];
#pragma unroll
  for (int g = 0; g < 2; g++) {
    float4 v0 = *(const float4*)(qptr + g * 32 + kg * 8);
    float4 v1 = *(const float4*)(qptr + g * 32 + kg * 8 + 4);
    float f[8] = {v0.x, v0.y, v0.z, v0.w, v1.x, v1.y, v1.z, v1.w};
#pragma unroll
    for (int j = 0; j < 8; j++) {
      float x = f[j] * 0.125f;
      bf16_t hh = (bf16_t)x;
      qh[g][j] = hh;
      ql[g][j] = (bf16_t)(x - (float)hh);
    }
  }

  f32x4 acc[4] = {};
  float mrow[4], lrow[4];
#pragma unroll
  for (int r = 0; r < 4; r++) { mrow[r] = -1e30f; lrow[r] = 0.f; }

  for (int kt = 0; kt <= qt; kt++) {
    __syncthreads();
    {
      int row = tid >> 2;
      int c0 = (tid & 3) * 16;
      const float* kr = qkv + (size_t)(b * S_ + kt * 64 + row) * 3072 + 1024 + h * 64 + c0;
      const float* vr = kr + 1024;
#pragma unroll
      for (int cc = 0; cc < 16; cc += 4) {
        float4 kv = *(const float4*)(kr + cc);
        float4 vv = *(const float4*)(vr + cc);
        float kf[4] = {kv.x, kv.y, kv.z, kv.w};
        float vf[4] = {vv.x, vv.y, vv.z, vv.w};
#pragma unroll
        for (int u = 0; u < 4; u++) {
          int c = c0 + cc + u;
          bf16_t hh = (bf16_t)kf[u];
          Ksh[row * 72 + c] = hh;
          Ksl[row * 72 + c] = (bf16_t)(kf[u] - (float)hh);
          bf16_t vh = (bf16_t)vf[u];
          Vth[c * 72 + row] = vh;
          Vtl[c * 72 + row] = (bf16_t)(vf[u] - (float)vh);
        }
      }
    }
    __syncthreads();

    f32x4 sc[4];
#pragma unroll
    for (int ni = 0; ni < 4; ni++) {
      f32x4 s = {};
#pragma unroll
      for (int g = 0; g < 2; g++) {
        int ro = (ni * 16 + lr) * 72 + g * 32 + kg * 8;
        bf16x8 kh = *(const bf16x8*)&Ksh[ro];
        bf16x8 kl = *(const bf16x8*)&Ksl[ro];
        s = __builtin_amdgcn_mfma_f32_16x16x32_bf16(qh[g], kh, s, 0, 0, 0);
        s = __builtin_amdgcn_mfma_f32_16x16x32_bf16(qh[g], kl, s, 0, 0, 0);
        s = __builtin_amdgcn_mfma_f32_16x16x32_bf16(ql[g], kh, s, 0, 0, 0);
      }
      sc[ni] = s;
    }

    int kbase = kt * 64;
    int myrow = qt * 64 + wave * 16 + kg * 4;
    if (kt == qt) {
#pragma unroll
      for (int ni = 0; ni < 4; ni++)
#pragma unroll
        for (int r = 0; r < 4; r++)
          if (kbase + ni * 16 + lr > myrow + r) sc[ni][r] = -1e30f;
    }

    float alpha[4];
#pragma unroll
    for (int r = 0; r < 4; r++) {
      float v = fmaxf(fmaxf(sc[0][r], sc[1][r]), fmaxf(sc[2][r], sc[3][r]));
#pragma unroll
      for (int o = 8; o; o >>= 1) v = fmaxf(v, __shfl_xor(v, o, 64));
      float mn = fmaxf(mrow[r], v);
      alpha[r] = __expf(mrow[r] - mn);
      mrow[r] = mn;
    }
    float rsum[4] = {0.f, 0.f, 0.f, 0.f};
#pragma unroll
    for (int ni = 0; ni < 4; ni++) {
#pragma unroll
      for (int r = 0; r < 4; r++) {
        float p = __expf(sc[ni][r] - mrow[r]);
        rsum[r] += p;
        bf16_t ph = (bf16_t)p;
        int po_ = (kg * 4 + r) * 72 + ni * 16 + lr;
        Ph[wave][po_] = ph;
        Pl[wave][po_] = (bf16_t)(p - (float)ph);
      }
    }
#pragma unroll
    for (int r = 0; r < 4; r++) {
      float v = rsum[r];
#pragma unroll
      for (int o = 8; o; o >>= 1) v += __shfl_xor(v, o, 64);
      lrow[r] = lrow[r] * alpha[r] + v;
    }
#pragma unroll
    for (int ni = 0; ni < 4; ni++)
#pragma unroll
      for (int r = 0; r < 4; r++) acc[ni][r] *= alpha[r];

    bf16x8 pfh[2], pfl[2];
#pragma unroll
    for (int g = 0; g < 2; g++) {
      int po_ = lr * 72 + g * 32 + kg * 8;
      pfh[g] = *(const bf16x8*)&Ph[wave][po_];
      pfl[g] = *(const bf16x8*)&Pl[wave][po_];
    }
#pragma unroll
    for (int ni = 0; ni < 4; ni++) {
#pragma unroll
      for (int g = 0; g < 2; g++) {
        int vo = (ni * 16 + lr) * 72 + g * 32 + kg * 8;
        bf16x8 vh = *(const bf16x8*)&Vth[vo];
        bf16x8 vl = *(const bf16x8*)&Vtl[vo];
        acc[ni] = __builtin_amdgcn_mfma_f32_16x16x32_bf16(pfh[g], vh, acc[ni], 0, 0, 0);
        acc[ni] = __builtin_amdgcn_mfma_f32_16x16x32_bf16(pfh[g], vl, acc[ni], 0, 0, 0);
        acc[ni] = __builtin_amdgcn_mfma_f32_16x16x32_bf16(pfl[g], vh, acc[ni], 0, 0, 0);
      }
    }
  }

  int trow = b * S_ + qt * 64 + wave * 16 + kg * 4;
#pragma unroll
  for (int r = 0; r < 4; r++) {
    float inv = 1.f / lrow[r];
#pragma unroll
    for (int ni = 0; ni < 4; ni++) {
      float x = acc[ni][r] * inv;
      bf16_t hh = (bf16_t)x;
      size_t idx = (size_t)(trow + r) * D_ + h * 64 + ni * 16 + lr;
      ctxh[idx] = hh;
      ctxl[idx] = (bf16_t)(x - (float)hh);
    }
  }
}

// ---------------- gate + grouped top-k routing ----------------
__global__ __launch_bounds__(64) void k_route(const float* __restrict__ h2,
    const float* __restrict__ gw, int* __restrict__ eidx, float* __restrict__ ew,
    int* __restrict__ cnt) {
  int t = blockIdx.x, lane = threadIdx.x;
  const float* x = h2 + (size_t)t * D_;
  float lg[8];
#pragma unroll
  for (int e = 0; e < 8; e++) {
    const float* w = gw + e * D_;
    float a = 0.f;
    for (int d = lane; d < D_; d += 64) a += x[d] * w[d];
#pragma unroll
    for (int o = 32; o; o >>= 1) a += __shfl_xor(a, o, 64);
    lg[e] = a;
  }
  if (lane == 0) {
    float mx = lg[0];
    for (int e = 1; e < 8; e++) mx = fmaxf(mx, lg[e]);
    float p[8], sum = 0.f;
    for (int e = 0; e < 8; e++) { p[e] = __expf(lg[e] - mx); sum += p[e]; }
    float inv = 1.f / sum;
    for (int e = 0; e < 8; e++) p[e] *= inv;
    float gs[4];
    for (int gi = 0; gi < 4; gi++) gs[gi] = fmaxf(p[2 * gi], p[2 * gi + 1]);
    int g0 = 0;
    for (int gi = 1; gi < 4; gi++) if (gs[gi] > gs[g0]) g0 = gi;
    int g1 = -1;
    for (int gi = 0; gi < 4; gi++) {
      if (gi == g0) continue;
      if (g1 < 0 || gs[gi] > gs[g1]) g1 = gi;
    }
    int i0 = -1, i1 = -1; float v0 = -1.f, v1 = -1.f;
    for (int e = 0; e < 8; e++) {
      int gi = e >> 1;
      if (gi != g0 && gi != g1) continue;
      if (p[e] > v0) { v1 = v0; i1 = i0; v0 = p[e]; i0 = e; }
      else if (p[e] > v1) { v1 = p[e]; i1 = e; }
    }
    eidx[2 * t] = i0; eidx[2 * t + 1] = i1;
    ew[2 * t] = v0; ew[2 * t + 1] = v1;
    atomicAdd(&cnt[i0], 1);
    atomicAdd(&cnt[i1], 1);
  }
}

// ---------------- offsets + tile table + rowtok init ----------------
__global__ __launch_bounds__(256) void k_offsets(const int* __restrict__ cnt,
    int* __restrict__ poff, int* __restrict__ te, int* __restrict__ tr0,
    int* __restrict__ trend, int* __restrict__ ntl, int* __restrict__ rowtok) {
  for (int i = threadIdx.x; i < RT_ROWS; i += 256) rowtok[i] = -1;
  if (threadIdx.x != 0) return;
  int offv = 0, nt = 0;
  for (int e = 0; e < 8; e++) {
    poff[e] = offv;
    int c = cnt[e];
    int ntile = (c + 127) >> 7;
    for (int i = 0; i < ntile; i++) {
      te[nt] = e; tr0[nt] = offv + i * 128; trend[nt] = offv + c; nt++;
    }
    offv += ntile << 7;
  }
  poff[8] = offv;
  // shared expert = expert 8, rows [RT_ROWS, ALL_ROWS)
  for (int i = 0; i < 16; i++) {
    te[nt] = 8; tr0[nt] = RT_ROWS + i * 128; trend[nt] = ALL_ROWS; nt++;
  }
  *ntl = nt;
}

__global__ __launch_bounds__(256) void k_fill(const int* __restrict__ eidx,
    const int* __restrict__ poff,
    int* __restrict__ cur, int* __restrict__ rowtok, int* __restrict__ postk) {
  int t = blockIdx.x * 256 + threadIdx.x;
  if (t >= T_) return;
#pragma unroll
  for (int k = 0; k < 2; k++) {
    int e = eidx[2 * t + k];
    int r = atomicAdd(&cur[e], 1);
    int pos = poff[e] + r;
    rowtok[pos] = t;
    postk[2 * t + k] = pos;
  }
}

__global__ __launch_bounds__(256) void k_gather(const int* __restrict__ rowtok,
    const bf16_t* __restrict__ h2h, const bf16_t* __restrict__ h2l,
    bf16_t* __restrict__ amh, bf16_t* __restrict__ aml) {
  int rrow = blockIdx.x;
  int tid = threadIdx.x;
  int t = rowtok[rrow];
  ushort4* dh = (ushort4*)(amh + (size_t)rrow * D_);
  ushort4* dl = (ushort4*)(aml + (size_t)rrow * D_);
  if (t < 0) {
    dh[tid] = make_ushort4(0, 0, 0, 0);
    dl[tid] = make_ushort4(0, 0, 0, 0);
  } else {
    dh[tid] = ((const ushort4*)(h2h + (size_t)t * D_))[tid];
    dl[tid] = ((const ushort4*)(h2l + (size_t)t * D_))[tid];
  }
}

// y += w0*outm[p0] + w1*outm[p1] + outm[RT_ROWS + t] (shared, weight 1)
__global__ __launch_bounds__(256) void k_scatter(const float* __restrict__ outm,
    const int* __restrict__ postk, const float* __restrict__ ewt,
    float* __restrict__ y) {
  int t = blockIdx.x, tid = threadIdx.x;
  int p0 = postk[2 * t], p1 = postk[2 * t + 1];
  float w0 = ewt[2 * t], w1 = ewt[2 * t + 1];
  float4* yr = (float4*)(y + (size_t)t * D_);
  const float4* a = (const float4*)(outm + (size_t)p0 * D_);
  const float4* b = (const float4*)(outm + (size_t)p1 * D_);
  const float4* s = (const float4*)(outm + (size_t)(RT_ROWS + t) * D_);
  float4 v = yr[tid], va = a[tid], vb = b[tid], vs = s[tid];
  v.x += w0 * va.x + w1 * vb.x + vs.x;
  v.y += w0 * va.y + w1 * vb.y + vs.y;
  v.z += w0 * va.z + w1 * vb.z + vs.z;
  v.w += w0 * va.w + w1 * vb.w + vs.w;
  yr[tid] = v;
}

extern "C" void kernel_launch(void* const* d_in, const int* in_sizes, int n_in,
                              void* d_out, int out_size, void* d_ws, size_t ws_size,
                              hipStream_t stream) {
  const float* src  = (const float*)d_in[0];
  const float* qkvw = (const float*)d_in[1];
  const float* qkvb = (const float*)d_in[2];
  const float* outw = (const float*)d_in[3];
  const float* outb = (const float*)d_in[4];
  const float* n1g  = (const float*)d_in[5];
  const float* n1b  = (const float*)d_in[6];
  const float* n2g  = (const float*)d_in[7];
  const float* n2b  = (const float*)d_in[8];
  const float* gw   = (const float*)d_in[9];
  const float* ew1  = (const float*)d_in[10];
  const float* eb1  = (const float*)d_in[11];
  const float* ew2  = (const float*)d_in[12];
  const float* eb2  = (const float*)d_in[13];
  const float* ew3  = (const float*)d_in[14];
  const float* eb3  = (const float*)d_in[15];
  const float* sw1  = (const float*)d_in[16];
  const float* sb1  = (const float*)d_in[17];
  const float* sw2  = (const float*)d_in[18];
  const float* sb2  = (const float*)d_in[19];
  const float* sw3  = (const float*)d_in[20];
  const float* sb3  = (const float*)d_in[21];
  const float* fng  = (const float*)d_in[22];
  const float* fnb  = (const float*)d_in[23];
  float* outp = (float*)d_out;

  char* base = (char*)d_ws;
  size_t off = 0;
  auto alloc = [&](size_t bytes) -> void* {
    off = (off + 255) & ~(size_t)255;
    void* r = base + off;
    off += bytes;
    return r;
  };
  bf16_t* wqkv_h  = (bf16_t*)alloc((size_t)3072 * 1024 * 2);
  bf16_t* wqkv_l  = (bf16_t*)alloc((size_t)3072 * 1024 * 2);
  bf16_t* wout_h  = (bf16_t*)alloc((size_t)1024 * 1024 * 2);
  bf16_t* wout_l  = (bf16_t*)alloc((size_t)1024 * 1024 * 2);
  bf16_t* we13_h  = (bf16_t*)alloc((size_t)9 * 2048 * 1024 * 2);  // interleaved w1/w3
  bf16_t* we13_l  = (bf16_t*)alloc((size_t)9 * 2048 * 1024 * 2);
  bf16_t* we2_h   = (bf16_t*)alloc((size_t)9 * 1024 * 1024 * 2);
  bf16_t* we2_l   = (bf16_t*)alloc((size_t)9 * 1024 * 1024 * 2);
  float*  ebc13   = (float*)alloc((size_t)9 * 2048 * 4);
  float*  eb2c    = (float*)alloc((size_t)9 * 1024 * 4);
  float*  y    = (float*)alloc((size_t)T_ * D_ * 4);
  float*  lnf  = (float*)alloc((size_t)T_ * D_ * 4);
  bf16_t* lnb_h = (bf16_t*)alloc((size_t)T_ * D_ * 2);
  bf16_t* lnb_l = (bf16_t*)alloc((size_t)T_ * D_ * 2);
  bf16_t* ctx_h = (bf16_t*)alloc((size_t)T_ * D_ * 2);
  bf16_t* ctx_l = (bf16_t*)alloc((size_t)T_ * D_ * 2);
  // regA union: qkvbuf (25.2MB) / outm (29.4MB)
  char* regA   = (char*)alloc((size_t)ALL_ROWS * 1024 * 4);
  float* qkvbuf = (float*)regA;
  float* outm   = (float*)regA;
  bf16_t* act_h  = (bf16_t*)alloc((size_t)ALL_ROWS * 1024 * 2);
  bf16_t* act_l  = (bf16_t*)alloc((size_t)ALL_ROWS * 1024 * 2);
  bf16_t* amoe_h = (bf16_t*)alloc((size_t)RT_ROWS * 1024 * 2);
  bf16_t* amoe_l = (bf16_t*)alloc((size_t)RT_ROWS * 1024 * 2);
  int*   eidx = (int*)alloc((size_t)T_ * 2 * 4);
  float* ewt  = (float*)alloc((size_t)T_ * 2 * 4);
  int* cnt  = (int*)alloc(64);
  int* cur  = (int*)alloc(64);
  int* poff = (int*)alloc(64);
  int* te   = (int*)alloc(256);
  int* tr0  = (int*)alloc(256);
  int* trend = (int*)alloc(256);
  int* ntl  = (int*)alloc(16);
  int* rowtok = (int*)alloc((size_t)RT_ROWS * 4);
  int* postk  = (int*)alloc((size_t)T_ * 2 * 4);
  (void)ws_size; (void)in_sizes; (void)n_in; (void)out_size;

  (void)hipMemcpyAsync(y, src, (size_t)T_ * D_ * 4, hipMemcpyDeviceToDevice, stream);

  for (int l = 0; l < 2; l++) {
    size_t lf = (size_t)l;
    k_cvtall<<<31744, 256, 0, stream>>>(
        qkvw + lf * 3145728, outw + lf * 1048576,
        ew1 + lf * 8388608, ew3 + lf * 8388608, ew2 + lf * 8388608,
        sw1 + lf * 1048576, sw3 + lf * 1048576, sw2 + lf * 1048576,
        wqkv_h, wqkv_l, wout_h, wout_l, we13_h, we13_l, we2_h, we2_l, cnt, cur);
    k_catbias<<<108, 256, 0, stream>>>(eb1 + lf * 8192, eb3 + lf * 8192,
        sb1 + lf * 1024, sb3 + lf * 1024, eb2 + lf * 8192, sb2 + lf * 1024,
        ebc13, eb2c);

    // LN1 -> split bf16
    k_ln<<<T_, 256, 0, stream>>>(y, n1g + lf * 1024, n1b + lf * 1024,
                                 (float*)nullptr, lnb_h, lnb_l);
    // QKV projection
    k_gemm<<<dim3(24, 16), 256, 0, stream>>>(lnb_h, lnb_l, wqkv_h, wqkv_l, qkvbuf,
                                             qkvb + lf * 3072, T_, 3072, 1024, 0);
    // flash attention -> ctx (split)
    k_attn<<<512, 256, 0, stream>>>(qkvbuf, ctx_h, ctx_l);
    // out projection, residual-add into y
    k_gemm<<<dim3(8, 16), 256, 0, stream>>>(ctx_h, ctx_l, wout_h, wout_l, y,
                                            outb + lf * 1024, T_, 1024, 1024, 1);
    // LN2 -> f32 + split bf16
    k_ln<<<T_, 256, 0, stream>>>(y, n2g + lf * 1024, n2b + lf * 1024, lnf, lnb_h, lnb_l);

    // routing (fp32 exact)
    k_route<<<T_, 64, 0, stream>>>(lnf, gw + lf * 8192, eidx, ewt, cnt);
    k_offsets<<<1, 256, 0, stream>>>(cnt, poff, te, tr0, trend, ntl, rowtok);
    k_fill<<<8, 256, 0, stream>>>(eidx, poff, cur, rowtok, postk);
    k_gather<<<RT_ROWS, 256, 0, stream>>>(rowtok, lnb_h, lnb_l, amoe_h, amoe_l);

    // up-GEMM (w1/w3 interleaved) with fused SwiGLU epilogue -> act planes
    k_gemm_up<<<dim3(16, MAX_TILES), 256, 0, stream>>>(amoe_h, amoe_l, lnb_h, lnb_l,
        we13_h, we13_l, act_h, act_l, ebc13, te, tr0, trend, ntl);
    // down-GEMM -> outm
    k_gemm_grp<<<dim3(8, MAX_TILES), 256, 0, stream>>>(act_h, act_l, we2_h, we2_l, outm,
        eb2c, te, tr0, trend, ntl, 1024, 1024);
    k_scatter<<<T_, 256, 0, stream>>>(outm, postk, ewt, y);
  }

  k_ln<<<T_, 256, 0, stream>>>(y, fng, fnb, outp, (bf16_t*)nullptr, (bf16_t*)nullptr);
}